// Round 3
// baseline (939.533 us; speedup 1.0000x reference)
//
#include <hip/hip_runtime.h>
#include <hip/hip_fp16.h>

#define NN 100   // nodes
#define HH 32    // hidden
#define BB 8192  // batch
#define DD 32    // dags
#define KP 128   // padded K (100 outs, 100..127 zero)

typedef _Float16 f16x8 __attribute__((ext_vector_type(8)));
typedef float f32x4 __attribute__((ext_vector_type(4)));
typedef unsigned short ushort_t;

union FU { uint4 u; f16x8 h; };

// ---- prep 1: x (B,N) -> xT (N,B)
__global__ void prep_xt(const float* __restrict__ x, float* __restrict__ xT) {
  int idx = blockIdx.x * 256 + threadIdx.x;
  if (idx >= BB * NN) return;
  int b = idx & (BB - 1);
  int n = idx >> 13;
  xT[idx] = x[(size_t)b * NN + n];
}

// ---- prep 2: W1 (N,H,N+1) -> W1A fp16 [N][H][KP] (outs-weights only, k>=100 zero)
__global__ void prep_w1a(const float* __restrict__ W1, ushort_t* __restrict__ W1A) {
  int idx = blockIdx.x * 256 + threadIdx.x;   // 100*32*128 = 409600 = 1600*256
  int node = idx >> 12;
  int rem = idx & 4095;
  int j = rem >> 7;
  int k = rem & 127;
  float v = (k < NN) ? W1[((size_t)node * HH + j) * (NN + 1) + k] : 0.f;
  W1A[idx] = __half_as_ushort(__float2half_rn(v));
}

// ---- prep 3: W1X[node][j] = x-weight (column 100) as f32
__global__ void prep_w1x(const float* __restrict__ W1, float* __restrict__ W1X) {
  int idx = blockIdx.x * 256 + threadIdx.x;   // 3200
  if (idx >= NN * HH) return;
  W1X[idx] = W1[(size_t)idx * (NN + 1) + NN];
}

// ---- prep 4: mask expansion: mexp[d][node][k] = 0xFFFF if input k active else 0
__global__ void prep_mexp(const float* __restrict__ A, ushort_t* __restrict__ mexp) {
  int idx = blockIdx.x * 256 + threadIdx.x;   // 32*100*128 = 409600
  int d = idx / 12800;
  int rem = idx - d * 12800;
  int node = rem >> 7;
  int k = rem & 127;
  ushort_t v = 0u;
  if (k < NN) v = (A[((size_t)d * NN + k) * NN + node] != 0.f) ? 0xFFFFu : 0u;
  mexp[idx] = v;
}

// ---- main: 4 waves/block, 32 batch rows per wave, outs^T in VGPRs as MFMA B-operand
__global__ __launch_bounds__(256, 4) void dag_mfma(
    const float* __restrict__ xT,      // [N][B]
    const int* __restrict__ order,     // [D][N]
    const int* __restrict__ do_idx_p,  // [1]
    const ushort_t* __restrict__ W1A,  // [N][H][KP] fp16
    const ushort_t* __restrict__ mexp, // [D][N][KP]
    const float* __restrict__ W1X,     // [N][H] f32 (x-weight)
    const float* __restrict__ b1,      // [N][H] f32
    const float* __restrict__ W2,      // [N][H]
    const float* __restrict__ b2,      // [N]
    float* __restrict__ out)           // [D][B][N]
{
  const int d = blockIdx.y;
  const int bx = blockIdx.x;
  const int tid = threadIdx.x;
  const int w = tid >> 6;
  const int lane = tid & 63;
  const int g = lane >> 4;      // k-octet group within wave
  const int n16 = lane & 15;    // batch-row within 16-tile
  const int di = __builtin_amdgcn_readfirstlane(do_idx_p[0]);
  const int rowbase = bx * 128 + w * 32 + n16;   // + nt*16

  // B-operand: breg[nt][S] = 8 fp16 of outs^T; lane(g,n16), slice S holds
  // k = 32S + 8g + {0..7} for batch row rowbase + 16*nt
  uint4 breg[2][4];
#pragma unroll
  for (int nt = 0; nt < 2; ++nt)
#pragma unroll
    for (int S = 0; S < 4; ++S) breg[nt][S] = make_uint4(0u, 0u, 0u, 0u);

  const int* ord = order + d * NN;
  const ushort_t* mbase_d = mexp + (size_t)d * NN * KP;

  // prefetch step 0's node and x-column
  int node = __builtin_amdgcn_readfirstlane(ord[0]);
  float xv0 = xT[(size_t)node * BB + rowbase];
  float xv1 = xT[(size_t)node * BB + rowbase + 16];

#pragma unroll 1
  for (int step = 0; step < NN; ++step) {
    // prefetch next step (hidden under this step's compute)
    const int node_next =
        __builtin_amdgcn_readfirstlane(ord[(step < NN - 1) ? step + 1 : step]);
    const float* xpn = xT + (size_t)node_next * BB + rowbase;
    const float xn0 = xpn[0];
    const float xn1 = xpn[16];

    float val[2];
    const float xvf[2] = {xv0, xv1};
    if (node != di) {
      const ushort_t* wb = W1A + (size_t)node * HH * KP;
      const ushort_t* mb = mbase_d + (size_t)node * KP;

      // j = 16*mt + 4*g + r4
      const float4 b1a = *(const float4*)(b1 + node * HH + 4 * g);
      const float4 b1b = *(const float4*)(b1 + node * HH + 16 + 4 * g);
      const float4 w2a = *(const float4*)(W2 + node * HH + 4 * g);
      const float4 w2b = *(const float4*)(W2 + node * HH + 16 + 4 * g);
      const float4 wxa = *(const float4*)(W1X + node * HH + 4 * g);
      const float4 wxb = *(const float4*)(W1X + node * HH + 16 + 4 * g);

      f32x4 acc[2][2];
#pragma unroll
      for (int nt = 0; nt < 2; ++nt) {
        acc[nt][0] = (f32x4){b1a.x, b1a.y, b1a.z, b1a.w};
        acc[nt][1] = (f32x4){b1b.x, b1b.y, b1b.z, b1b.w};
      }

      __builtin_amdgcn_s_setprio(1);
#pragma unroll
      for (int S = 0; S < 4; ++S) {
        const int koff = 32 * S + 8 * g;
        FU a0, a1, mk;
        a0.u = *(const uint4*)(wb + n16 * KP + koff);          // j = n16
        a1.u = *(const uint4*)(wb + (16 + n16) * KP + koff);   // j = 16+n16
        mk.u = *(const uint4*)(mb + koff);
        a0.u.x &= mk.u.x; a0.u.y &= mk.u.y; a0.u.z &= mk.u.z; a0.u.w &= mk.u.w;
        a1.u.x &= mk.u.x; a1.u.y &= mk.u.y; a1.u.z &= mk.u.z; a1.u.w &= mk.u.w;
#pragma unroll
        for (int nt = 0; nt < 2; ++nt) {
          FU bu; bu.u = breg[nt][S];
          acc[nt][0] = __builtin_amdgcn_mfma_f32_16x16x32_f16(a0.h, bu.h, acc[nt][0], 0, 0, 0);
          acc[nt][1] = __builtin_amdgcn_mfma_f32_16x16x32_f16(a1.h, bu.h, acc[nt][1], 0, 0, 0);
        }
      }
      __builtin_amdgcn_s_setprio(0);

      const float b2n = b2[node];
      const float wa[4] = {w2a.x, w2a.y, w2a.z, w2a.w};
      const float wbv[4] = {w2b.x, w2b.y, w2b.z, w2b.w};
      const float xa[4] = {wxa.x, wxa.y, wxa.z, wxa.w};
      const float xb[4] = {wxb.x, wxb.y, wxb.z, wxb.w};
#pragma unroll
      for (int nt = 0; nt < 2; ++nt) {
        float p = 0.f;
#pragma unroll
        for (int r4 = 0; r4 < 4; ++r4) {
          float h0 = fmaf(xa[r4], xvf[nt], acc[nt][0][r4]);
          h0 = fmaxf(h0, 0.01f * h0);
          p = fmaf(wa[r4], h0, p);
          float h1 = fmaf(xb[r4], xvf[nt], acc[nt][1][r4]);
          h1 = fmaxf(h1, 0.01f * h1);
          p = fmaf(wbv[r4], h1, p);
        }
        p += __shfl_xor(p, 16, 64);
        p += __shfl_xor(p, 32, 64);
        val[nt] = p + b2n;
      }
    } else {
      val[0] = xvf[0];
      val[1] = xvf[1];
    }

    // insert val (fp16) at k=node: S=node>>5, comp=(node>>1)&3, half=node&1,
    // owner g == (node>>3)&3 — all wave-uniform selects
    const int sn = node >> 5;
    const int en2 = (node >> 1) & 3;
    const int gn = (node >> 3) & 3;
    const int hin = node & 1;
    const bool own = (g == gn);
    ushort_t hv[2];
    hv[0] = __half_as_ushort(__float2half_rn(val[0]));
    hv[1] = __half_as_ushort(__float2half_rn(val[1]));
#pragma unroll
    for (int S = 0; S < 4; ++S) {
      if (S != sn) continue;        // uniform
#pragma unroll
      for (int nt = 0; nt < 2; ++nt) {
        uint4& Bq = breg[nt][S];
        uint hvn = (uint)hv[nt];
        if (en2 == 0) {
          uint old = Bq.x;
          uint nw = hin ? ((old & 0x0000FFFFu) | (hvn << 16)) : ((old & 0xFFFF0000u) | hvn);
          Bq.x = own ? nw : old;
        } else if (en2 == 1) {
          uint old = Bq.y;
          uint nw = hin ? ((old & 0x0000FFFFu) | (hvn << 16)) : ((old & 0xFFFF0000u) | hvn);
          Bq.y = own ? nw : old;
        } else if (en2 == 2) {
          uint old = Bq.z;
          uint nw = hin ? ((old & 0x0000FFFFu) | (hvn << 16)) : ((old & 0xFFFF0000u) | hvn);
          Bq.z = own ? nw : old;
        } else {
          uint old = Bq.w;
          uint nw = hin ? ((old & 0x0000FFFFu) | (hvn << 16)) : ((old & 0xFFFF0000u) | hvn);
          Bq.w = own ? nw : old;
        }
      }
    }

    node = node_next;
    xv0 = xn0;
    xv1 = xn1;
  }

  // ---- output: per-wave 32-row LDS transpose chunks, coalesced f32 stores
  __shared__ ushort_t tbuf[32 * 132];
  for (int c = 0; c < 4; ++c) {
    __syncthreads();
    if (w == c) {
#pragma unroll
      for (int nt = 0; nt < 2; ++nt) {
        int r = nt * 16 + n16;
#pragma unroll
        for (int S = 0; S < 4; ++S) {
          int k = 32 * S + 8 * g;
          *(uint2*)&tbuf[r * 132 + k] = make_uint2(breg[nt][S].x, breg[nt][S].y);
          *(uint2*)&tbuf[r * 132 + k + 4] = make_uint2(breg[nt][S].z, breg[nt][S].w);
        }
      }
    }
    __syncthreads();
    const size_t obase = ((size_t)d * BB + bx * 128 + c * 32) * NN;
    for (int idx = tid; idx < 32 * NN; idx += 256) {
      int rl = idx / NN;
      int col = idx - rl * NN;
      out[obase + idx] = __half2float(__ushort_as_half(tbuf[rl * 132 + col]));
    }
  }
}

extern "C" void kernel_launch(void* const* d_in, const int* in_sizes, int n_in,
                              void* d_out, int out_size, void* d_ws, size_t ws_size,
                              hipStream_t stream) {
  const float* x     = (const float*)d_in[0];
  const float* A     = (const float*)d_in[1];
  const int* order   = (const int*)d_in[2];
  const int* do_idx  = (const int*)d_in[3];
  const float* W1    = (const float*)d_in[4];
  const float* b1    = (const float*)d_in[5];
  const float* W2    = (const float*)d_in[6];
  const float* b2    = (const float*)d_in[7];
  float* out = (float*)d_out;

  char* ws = (char*)d_ws;
  float* xT       = (float*)ws;                          // 3,276,800 B
  ushort_t* W1A   = (ushort_t*)(ws + 3276800);           // 819,200 B
  ushort_t* mexp  = (ushort_t*)(ws + 3276800 + 819200);  // 819,200 B
  float* W1X      = (float*)(ws + 3276800 + 819200 + 819200);  // 12,800 B

  hipLaunchKernelGGL(prep_xt, dim3((BB * NN) / 256), dim3(256), 0, stream, x, xT);
  hipLaunchKernelGGL(prep_w1a, dim3(1600), dim3(256), 0, stream, W1, W1A);
  hipLaunchKernelGGL(prep_w1x, dim3((NN * HH + 255) / 256), dim3(256), 0, stream, W1, W1X);
  hipLaunchKernelGGL(prep_mexp, dim3(1600), dim3(256), 0, stream, A, mexp);
  hipLaunchKernelGGL(dag_mfma, dim3(BB / 128, DD), dim3(256), 0, stream,
                     xT, order, do_idx, W1A, mexp, W1X, b1, W2, b2, out);
}

// Round 4
// 414.410 us; speedup vs baseline: 2.2672x; 2.2672x over previous
//
#include <hip/hip_runtime.h>
#include <hip/hip_fp16.h>

#define NN 100   // nodes
#define HH 32    // hidden
#define BB 8192  // batch
#define DD 32    // dags
#define KP 128   // padded K (100 outs, 100..127 zero)
#define TPB 512  // 8 waves per block

typedef _Float16 f16x8 __attribute__((ext_vector_type(8)));
typedef float f32x4 __attribute__((ext_vector_type(4)));
typedef unsigned short ushort_t;
union FU { uint4 u; f16x8 h; };

#define AS_GLOBAL __attribute__((address_space(1)))
#define AS_LDS    __attribute__((address_space(3)))

// ---- LDS layout (bytes)
// epi   @ 0     : 100 nodes x 100 f32  = 40000   [b1(32)|W2(32)|W1X(32)|b2|pad3]
// mexp  @ 40000 : 100 x 128 ushort     = 25600
// stage @ 65600 : 2 x 8192 (W1A tile)  = 16384
// total 81984; tbuf (16896B) reuses @40000 after main loop
#define EPI_OFF 0
#define MEXP_OFF 40000
#define STAGE_OFF 65600
#define SMEM_BYTES 81984

// ---- prep 1: x (B,N) -> xT (N,B)
__global__ void prep_xt(const float* __restrict__ x, float* __restrict__ xT) {
  int idx = blockIdx.x * 256 + threadIdx.x;
  if (idx >= BB * NN) return;
  int b = idx & (BB - 1);
  int n = idx >> 13;
  xT[idx] = x[(size_t)b * NN + n];
}

// ---- prep 2: W1 -> W1A fp16, PRE-SWIZZLED per-node 32x128 tile
// halfword index within tile: (j*128 + k) ^ ((j&7)<<3)
__global__ void prep_w1a(const float* __restrict__ W1, ushort_t* __restrict__ W1A) {
  int idx = blockIdx.x * 256 + threadIdx.x;   // 100*32*128 = 409600
  int node = idx >> 12;
  int rem = idx & 4095;
  int j = rem >> 7;
  int k = rem & 127;
  float v = (k < NN) ? W1[((size_t)node * HH + j) * (NN + 1) + k] : 0.f;
  int t = (j * KP + k) ^ ((j & 7) << 3);
  W1A[(size_t)node * 4096 + t] = __half_as_ushort(__float2half_rn(v));
}

// ---- prep 3: mask expansion mexp[d][node][k]
__global__ void prep_mexp(const float* __restrict__ A, ushort_t* __restrict__ mexp) {
  int idx = blockIdx.x * 256 + threadIdx.x;   // 409600
  int d = idx / 12800;
  int rem = idx - d * 12800;
  int node = rem >> 7;
  int k = rem & 127;
  ushort_t v = 0u;
  if (k < NN) v = (A[((size_t)d * NN + k) * NN + node] != 0.f) ? 0xFFFFu : 0u;
  mexp[idx] = v;
}

// ---- prep 4: epilogue pack epi[node][100] = b1(32)|W2(32)|W1X(32)|b2|pad
__global__ void prep_epi(const float* __restrict__ b1, const float* __restrict__ W2,
                         const float* __restrict__ W1, const float* __restrict__ b2,
                         float* __restrict__ epi) {
  int idx = blockIdx.x * 256 + threadIdx.x;
  if (idx >= NN * 100) return;
  int node = idx / 100;
  int c = idx - node * 100;
  float v = 0.f;
  if (c < 32) v = b1[node * HH + c];
  else if (c < 64) v = W2[node * HH + (c - 32)];
  else if (c < 96) v = W1[((size_t)node * HH + (c - 64)) * (NN + 1) + NN];
  else if (c == 96) v = b2[node];
  epi[idx] = v;
}

// ---- main: 8 waves/block share one dag; 64 rows/wave; LDS-staged weights
__global__ __launch_bounds__(TPB, 2) void dag_mfma(
    const float* __restrict__ xT,      // [N][B]
    const int* __restrict__ order,     // [D][N]
    const int* __restrict__ do_idx_p,  // [1]
    const ushort_t* __restrict__ W1A,  // [N][4096] fp16, swizzled tiles
    const ushort_t* __restrict__ mexp_g, // [D][N][KP]
    const float* __restrict__ epi_g,   // [N][100]
    float* __restrict__ out)           // [D][B][N]
{
  __shared__ __align__(16) char smem[SMEM_BYTES];
  float* epi_l = (float*)(smem + EPI_OFF);
  ushort_t* mexp_l = (ushort_t*)(smem + MEXP_OFF);
  ushort_t* stage = (ushort_t*)(smem + STAGE_OFF);   // [2][4096] halfs

  const int d = blockIdx.y;
  const int bx = blockIdx.x;
  const int tid = threadIdx.x;
  const int w = tid >> 6;
  const int lane = tid & 63;
  const int g = lane >> 4;
  const int n16 = lane & 15;
  const int di = __builtin_amdgcn_readfirstlane(do_idx_p[0]);
  const int rowbase = bx * 512 + w * 64 + n16;

  // ---- block preloads: epi (2500 uint4), mexp[d] (1600 uint4)
  {
    const uint4* s4 = (const uint4*)epi_g;
    uint4* d4 = (uint4*)epi_l;
    for (int i = tid; i < 2500; i += TPB) d4[i] = s4[i];
    const uint4* m4 = (const uint4*)(mexp_g + (size_t)d * NN * KP);
    uint4* md = (uint4*)mexp_l;
    for (int i = tid; i < 1600; i += TPB) md[i] = m4[i];
  }

  const int* ord = order + d * NN;
  int node = __builtin_amdgcn_readfirstlane(ord[0]);

  // stage step-0 tile (8KB): 512 threads x 16B via global_load_lds
  {
    const ushort_t* gsrc = W1A + (size_t)node * 4096 + tid * 8;
    ushort_t* ldst = stage + (w << 9);               // wave-uniform base
    __builtin_amdgcn_global_load_lds((const AS_GLOBAL void*)gsrc,
                                     (AS_LDS void*)ldst, 16, 0, 0);
  }

  // x prefetch for step 0
  float xv[4];
  {
    const float* xp = xT + (size_t)node * BB + rowbase;
#pragma unroll
    for (int nt = 0; nt < 4; ++nt) xv[nt] = xp[nt * 16];
  }

  // B-operand: breg[nt][S]: lane(g,n16) holds k=32S+8g+{0..7} for row rowbase+16nt
  uint4 breg[4][4];
#pragma unroll
  for (int nt = 0; nt < 4; ++nt)
#pragma unroll
    for (int S = 0; S < 4; ++S) breg[nt][S] = make_uint4(0u, 0u, 0u, 0u);

  __syncthreads();   // epi+mexp+stage0 ready (drains vmcnt+lgkmcnt)

  int cur = 0;
#pragma unroll 1
  for (int step = 0; step < NN; ++step) {
    const int node_next =
        __builtin_amdgcn_readfirstlane(ord[(step < NN - 1) ? step + 1 : step]);

    // issue next-step stage into the other buffer (drained at this step's barrier)
    {
      const ushort_t* gsrc = W1A + (size_t)node_next * 4096 + tid * 8;
      ushort_t* ldst = stage + ((cur ^ 1) << 12) + (w << 9);
      __builtin_amdgcn_global_load_lds((const AS_GLOBAL void*)gsrc,
                                       (AS_LDS void*)ldst, 16, 0, 0);
    }
    // prefetch next x column
    float xn[4];
    {
      const float* xp = xT + (size_t)node_next * BB + rowbase;
#pragma unroll
      for (int nt = 0; nt < 4; ++nt) xn[nt] = xp[nt * 16];
    }

    float val[4];
    if (node != di) {
      const float* ep = epi_l + node * 100;
      const float4 b1a = *(const float4*)(ep + 4 * g);
      const float4 b1b = *(const float4*)(ep + 16 + 4 * g);
      const float4 w2a = *(const float4*)(ep + 32 + 4 * g);
      const float4 w2b = *(const float4*)(ep + 48 + 4 * g);
      const float4 wxa = *(const float4*)(ep + 64 + 4 * g);
      const float4 wxb = *(const float4*)(ep + 80 + 4 * g);
      const float b2n = ep[96];

      f32x4 acc[4][2];
#pragma unroll
      for (int nt = 0; nt < 4; ++nt) {
        acc[nt][0] = (f32x4){b1a.x, b1a.y, b1a.z, b1a.w};
        acc[nt][1] = (f32x4){b1b.x, b1b.y, b1b.z, b1b.w};
      }

      const ushort_t* sb = stage + (cur << 12);
      const ushort_t* mb = mexp_l + node * KP;

      __builtin_amdgcn_s_setprio(1);
#pragma unroll
      for (int S = 0; S < 4; ++S) {
        const int koff = 32 * S + 8 * g;
        const int h0 = (n16 * KP + koff) ^ ((n16 & 7) << 3);
        const int h1 = ((16 + n16) * KP + koff) ^ ((n16 & 7) << 3);
        FU a0, a1, mk;
        a0.u = *(const uint4*)(sb + h0);
        a1.u = *(const uint4*)(sb + h1);
        mk.u = *(const uint4*)(mb + koff);
        a0.u.x &= mk.u.x; a0.u.y &= mk.u.y; a0.u.z &= mk.u.z; a0.u.w &= mk.u.w;
        a1.u.x &= mk.u.x; a1.u.y &= mk.u.y; a1.u.z &= mk.u.z; a1.u.w &= mk.u.w;
#pragma unroll
        for (int nt = 0; nt < 4; ++nt) {
          FU bu; bu.u = breg[nt][S];
          acc[nt][0] = __builtin_amdgcn_mfma_f32_16x16x32_f16(a0.h, bu.h, acc[nt][0], 0, 0, 0);
          acc[nt][1] = __builtin_amdgcn_mfma_f32_16x16x32_f16(a1.h, bu.h, acc[nt][1], 0, 0, 0);
        }
      }
      __builtin_amdgcn_s_setprio(0);

      const float wa[4] = {w2a.x, w2a.y, w2a.z, w2a.w};
      const float wbv[4] = {w2b.x, w2b.y, w2b.z, w2b.w};
      const float xa[4] = {wxa.x, wxa.y, wxa.z, wxa.w};
      const float xb[4] = {wxb.x, wxb.y, wxb.z, wxb.w};
#pragma unroll
      for (int nt = 0; nt < 4; ++nt) {
        float p = 0.f;
#pragma unroll
        for (int r4 = 0; r4 < 4; ++r4) {
          float h0 = fmaf(xa[r4], xv[nt], acc[nt][0][r4]);
          h0 = fmaxf(h0, 0.01f * h0);
          p = fmaf(wa[r4], h0, p);
          float h1 = fmaf(xb[r4], xv[nt], acc[nt][1][r4]);
          h1 = fmaxf(h1, 0.01f * h1);
          p = fmaf(wbv[r4], h1, p);
        }
        p += __shfl_xor(p, 16, 64);
        p += __shfl_xor(p, 32, 64);
        val[nt] = p + b2n;
      }
    } else {
#pragma unroll
      for (int nt = 0; nt < 4; ++nt) val[nt] = xv[nt];
    }

    // insert val (fp16) at k=node (wave-uniform selects)
    const int sn = node >> 5;
    const int en2 = (node >> 1) & 3;
    const int gn = (node >> 3) & 3;
    const int hin = node & 1;
    const bool own = (g == gn);
    ushort_t hv[4];
#pragma unroll
    for (int nt = 0; nt < 4; ++nt) hv[nt] = __half_as_ushort(__float2half_rn(val[nt]));
#pragma unroll
    for (int S = 0; S < 4; ++S) {
      if (S != sn) continue;    // uniform
#pragma unroll
      for (int nt = 0; nt < 4; ++nt) {
        uint4& Bq = breg[nt][S];
        uint hvn = (uint)hv[nt];
        if (en2 == 0) {
          uint old = Bq.x;
          uint nw = hin ? ((old & 0x0000FFFFu) | (hvn << 16)) : ((old & 0xFFFF0000u) | hvn);
          Bq.x = own ? nw : old;
        } else if (en2 == 1) {
          uint old = Bq.y;
          uint nw = hin ? ((old & 0x0000FFFFu) | (hvn << 16)) : ((old & 0xFFFF0000u) | hvn);
          Bq.y = own ? nw : old;
        } else if (en2 == 2) {
          uint old = Bq.z;
          uint nw = hin ? ((old & 0x0000FFFFu) | (hvn << 16)) : ((old & 0xFFFF0000u) | hvn);
          Bq.z = own ? nw : old;
        } else {
          uint old = Bq.w;
          uint nw = hin ? ((old & 0x0000FFFFu) | (hvn << 16)) : ((old & 0xFFFF0000u) | hvn);
          Bq.w = own ? nw : old;
        }
      }
    }

    __syncthreads();   // stage[cur^1] landed; all waves done with stage[cur]
    cur ^= 1;
    node = node_next;
#pragma unroll
    for (int nt = 0; nt < 4; ++nt) xv[nt] = xn[nt];
  }

  // ---- output: per-wave 64-row LDS transpose chunks (tbuf reuses mexp area)
  ushort_t* tbuf = (ushort_t*)(smem + MEXP_OFF);   // 64*132 halfs = 16896B
  for (int c = 0; c < 8; ++c) {
    __syncthreads();
    if (w == c) {
#pragma unroll
      for (int nt = 0; nt < 4; ++nt) {
        int r = nt * 16 + n16;
#pragma unroll
        for (int S = 0; S < 4; ++S) {
          int k = 32 * S + 8 * g;
          *(uint2*)&tbuf[r * 132 + k] = make_uint2(breg[nt][S].x, breg[nt][S].y);
          *(uint2*)&tbuf[r * 132 + k + 4] = make_uint2(breg[nt][S].z, breg[nt][S].w);
        }
      }
    }
    __syncthreads();
    const size_t obase = ((size_t)d * BB + bx * 512 + c * 64) * NN;
    for (int idx = tid; idx < 64 * NN; idx += TPB) {
      int rl = idx / NN;
      int col = idx - rl * NN;
      out[obase + idx] = __half2float(__ushort_as_half(tbuf[rl * 132 + col]));
    }
  }
}

extern "C" void kernel_launch(void* const* d_in, const int* in_sizes, int n_in,
                              void* d_out, int out_size, void* d_ws, size_t ws_size,
                              hipStream_t stream) {
  const float* x     = (const float*)d_in[0];
  const float* A     = (const float*)d_in[1];
  const int* order   = (const int*)d_in[2];
  const int* do_idx  = (const int*)d_in[3];
  const float* W1    = (const float*)d_in[4];
  const float* b1    = (const float*)d_in[5];
  const float* W2    = (const float*)d_in[6];
  const float* b2    = (const float*)d_in[7];
  float* out = (float*)d_out;

  char* ws = (char*)d_ws;
  float* xT       = (float*)ws;                               // 3,276,800 B
  ushort_t* W1A   = (ushort_t*)(ws + 3276800);                // 819,200 B
  ushort_t* mexp  = (ushort_t*)(ws + 3276800 + 819200);       // 819,200 B
  float* epi      = (float*)(ws + 3276800 + 819200 + 819200); // 40,000 B

  hipLaunchKernelGGL(prep_xt, dim3((BB * NN) / 256), dim3(256), 0, stream, x, xT);
  hipLaunchKernelGGL(prep_w1a, dim3(1600), dim3(256), 0, stream, W1, W1A);
  hipLaunchKernelGGL(prep_mexp, dim3(1600), dim3(256), 0, stream, A, mexp);
  hipLaunchKernelGGL(prep_epi, dim3((NN * 100 + 255) / 256), dim3(256), 0, stream,
                     b1, W2, W1, b2, epi);
  hipLaunchKernelGGL(dag_mfma, dim3(BB / 512, DD), dim3(512), 0, stream,
                     xT, order, do_idx, W1A, mexp, epi, out);
}

// Round 5
// 332.121 us; speedup vs baseline: 2.8289x; 1.2478x over previous
//
#include <hip/hip_runtime.h>
#include <hip/hip_fp16.h>

#define NN 100   // nodes
#define HH 32    // hidden
#define BB 8192  // batch
#define DD 32    // dags
#define KP 128   // padded K
#define TPB 512  // 8 waves per block

typedef _Float16 f16x8 __attribute__((ext_vector_type(8)));
typedef float f32x4 __attribute__((ext_vector_type(4)));
typedef unsigned short ushort_t;
union FU { uint4 u; f16x8 h; };

#define AS_GLOBAL __attribute__((address_space(1)))
#define AS_LDS    __attribute__((address_space(3)))

// ======================= shared prep =======================
__global__ void prep_xt(const float* __restrict__ x, float* __restrict__ xT) {
  int idx = blockIdx.x * 256 + threadIdx.x;
  if (idx >= BB * NN) return;
  int b = idx & (BB - 1);
  int n = idx >> 13;
  xT[idx] = x[(size_t)b * NN + n];
}

// ======================= variant A (pre-masked) =======================
// W1M[d][node]: 32x128 fp16 tile, swizzled (j*128+k)^((j&7)<<3)
// k<100: mask*W1; k==100: x-weight; k==101: b1; else 0
__global__ void prep_w1m(const float* __restrict__ A, const float* __restrict__ W1,
                         const float* __restrict__ b1, ushort_t* __restrict__ W1M) {
  int idx = blockIdx.x * 256 + threadIdx.x;   // DD*NN*4096 = 13,107,200
  int tile = idx >> 12;           // d*NN + node
  int d = tile / NN;
  int node = tile - d * NN;
  int rem = idx & 4095;
  int j = rem >> 7;
  int k = rem & 127;
  float v = 0.f;
  if (k < NN) {
    float m = A[((size_t)d * NN + k) * NN + node];
    v = (m != 0.f) ? W1[((size_t)node * HH + j) * (NN + 1) + k] : 0.f;
  } else if (k == NN) {
    v = W1[((size_t)node * HH + j) * (NN + 1) + NN];
  } else if (k == NN + 1) {
    v = b1[node * HH + j];
  }
  int t = (j * KP + k) ^ ((j & 7) << 3);
  W1M[(size_t)tile * 4096 + t] = __half_as_ushort(__float2half_rn(v));
}

// epi2[node][36] = W2(32) | b2 | pad3
__global__ void prep_epi2(const float* __restrict__ W2, const float* __restrict__ b2,
                          float* __restrict__ epi) {
  int idx = blockIdx.x * 256 + threadIdx.x;
  if (idx >= NN * 36) return;
  int node = idx / 36;
  int c = idx - node * 36;
  float v = 0.f;
  if (c < 32) v = W2[node * HH + c];
  else if (c == 32) v = b2[node];
  epi[idx] = v;
}

// LDS: epi 14400 @0; stage 4x8192 @14464; total 47232; tbuf(16896) reuses @0
#define A_STAGE_OFF 14464
#define A_SMEM 47232

__global__ __launch_bounds__(TPB, 4) void dag_mfma_pm(
    const float* __restrict__ xT,      // [N][B]
    const int* __restrict__ order,     // [D][N]
    const int* __restrict__ do_idx_p,  // [1]
    const ushort_t* __restrict__ W1M,  // [D][N][4096] fp16 swizzled
    const float* __restrict__ epi_g,   // [N][36]
    float* __restrict__ out)           // [D][B][N]
{
  __shared__ __align__(16) char smem[A_SMEM];
  float* epi_l = (float*)smem;
  ushort_t* stage = (ushort_t*)(smem + A_STAGE_OFF);

  const int d = blockIdx.y;
  const int bx = blockIdx.x;
  const int tid = threadIdx.x;
  const int w = tid >> 6;
  const int lane = tid & 63;
  const int g = lane >> 4;
  const int n16 = lane & 15;
  const int di = __builtin_amdgcn_readfirstlane(do_idx_p[0]);
  const int rowbase = bx * 512 + w * 64 + n16;

  // epi preload (900 uint4)
  {
    const uint4* s4 = (const uint4*)epi_g;
    uint4* d4 = (uint4*)epi_l;
    for (int i = tid; i < 900; i += TPB) d4[i] = s4[i];
  }

  const ushort_t* Wd = W1M + (size_t)d * NN * 4096;
  const int* ord = order + d * NN;

  // node pipeline: n_cur=ord[t], n_p1=ord[t+1], n_p2=ord[t+2], ordv=ord[t+3] in flight
  int ordv = ord[3];
  int n_cur = __builtin_amdgcn_readfirstlane(ord[0]);
  int n_p1  = __builtin_amdgcn_readfirstlane(ord[1]);
  int n_p2  = __builtin_amdgcn_readfirstlane(ord[2]);

  // stage tiles 0,1
  {
    const ushort_t* g0 = Wd + (size_t)n_cur * 4096 + tid * 8;
    __builtin_amdgcn_global_load_lds((const AS_GLOBAL void*)g0,
        (AS_LDS void*)(stage + (w << 9)), 16, 0, 0);
    const ushort_t* g1 = Wd + (size_t)n_p1 * 4096 + tid * 8;
    __builtin_amdgcn_global_load_lds((const AS_GLOBAL void*)g1,
        (AS_LDS void*)(stage + 4096 + (w << 9)), 16, 0, 0);
  }
  // x(0)
  float xc[4];
  {
    const float* xp = xT + (size_t)n_cur * BB + rowbase;
#pragma unroll
    for (int nt = 0; nt < 4; ++nt) xc[nt] = xp[nt * 16];
  }

  // B-operand: breg[nt][S]: lane(g,n16) holds k=32S+8g+{0..7}, row rowbase+16nt
  // k=101 (S=3,.z hi, g==0) = constant 1.0 (b1 row); k=100 (.z lo) = per-step x
  uint4 breg[4][4];
#pragma unroll
  for (int nt = 0; nt < 4; ++nt) {
#pragma unroll
    for (int S = 0; S < 4; ++S) breg[nt][S] = make_uint4(0u, 0u, 0u, 0u);
    breg[nt][3].z = (g == 0) ? 0x3C000000u : 0u;
  }

  const f32x4 zero4 = {0.f, 0.f, 0.f, 0.f};

  __syncthreads();   // epi visible (prologue full drain, once)

#pragma unroll 1
  for (int t = 0; t < NN; ++t) {
    const int n_p3 = __builtin_amdgcn_readfirstlane(ordv);
    ordv = ord[(t + 4 < NN) ? t + 4 : NN - 1];               // VMEM 1
    {
      const ushort_t* gs = Wd + (size_t)n_p2 * 4096 + tid * 8;
      ushort_t* ldst = stage + (((t + 2) & 3) << 12) + (w << 9);
      __builtin_amdgcn_global_load_lds((const AS_GLOBAL void*)gs,
                                       (AS_LDS void*)ldst, 16, 0, 0);  // VMEM 2
    }
    float xn[4];
    {
      const float* xp = xT + (size_t)n_p1 * BB + rowbase;
#pragma unroll
      for (int nt = 0; nt < 4; ++nt) xn[nt] = xp[nt * 16];   // VMEM 3-6
    }

    // tile(t)+x(t) issued >=6 VMEM ops ago -> counted wait, never drain prefetch
    asm volatile("s_waitcnt vmcnt(6)" ::: "memory");
    __builtin_amdgcn_s_barrier();
    __builtin_amdgcn_sched_barrier(0);

    // insert x(t) at k=100 (S=3, .z lo, owner g==0)
#pragma unroll
    for (int nt = 0; nt < 4; ++nt) {
      uint old = breg[nt][3].z;
      uint ins = (old & 0xFFFF0000u) |
                 (uint)__half_as_ushort(__float2half_rn(xc[nt]));
      breg[nt][3].z = (g == 0) ? ins : old;
    }

    float val[4];
    if (n_cur != di) {
      const ushort_t* sb = stage + ((t & 3) << 12);
      const float* ep = epi_l + n_cur * 36;
      const float4 w2a = *(const float4*)(ep + 4 * g);        // j=4g+r4
      const float4 w2b = *(const float4*)(ep + 16 + 4 * g);   // j=16+4g+r4
      const float b2n = ep[32];

      f32x4 acc[4][2];
      __builtin_amdgcn_s_setprio(1);
#pragma unroll
      for (int S = 0; S < 4; ++S) {
        const int koff = 32 * S + 8 * g;
        const int h0 = (n16 * KP + koff) ^ ((n16 & 7) << 3);
        const int h1 = ((16 + n16) * KP + koff) ^ ((n16 & 7) << 3);
        FU a0, a1;
        a0.u = *(const uint4*)(sb + h0);
        a1.u = *(const uint4*)(sb + h1);
#pragma unroll
        for (int nt = 0; nt < 4; ++nt) {
          FU bu; bu.u = breg[nt][S];
          if (S == 0) {
            acc[nt][0] = __builtin_amdgcn_mfma_f32_16x16x32_f16(a0.h, bu.h, zero4, 0, 0, 0);
            acc[nt][1] = __builtin_amdgcn_mfma_f32_16x16x32_f16(a1.h, bu.h, zero4, 0, 0, 0);
          } else {
            acc[nt][0] = __builtin_amdgcn_mfma_f32_16x16x32_f16(a0.h, bu.h, acc[nt][0], 0, 0, 0);
            acc[nt][1] = __builtin_amdgcn_mfma_f32_16x16x32_f16(a1.h, bu.h, acc[nt][1], 0, 0, 0);
          }
        }
      }
      __builtin_amdgcn_s_setprio(0);

      const float wa[4] = {w2a.x, w2a.y, w2a.z, w2a.w};
      const float wbv[4] = {w2b.x, w2b.y, w2b.z, w2b.w};
#pragma unroll
      for (int nt = 0; nt < 4; ++nt) {
        float p = 0.f;
#pragma unroll
        for (int r4 = 0; r4 < 4; ++r4) {
          float h0 = acc[nt][0][r4]; h0 = fmaxf(h0, 0.01f * h0);
          p = fmaf(wa[r4], h0, p);
          float h1 = acc[nt][1][r4]; h1 = fmaxf(h1, 0.01f * h1);
          p = fmaf(wbv[r4], h1, p);
        }
        p += __shfl_xor(p, 16, 64);
        p += __shfl_xor(p, 32, 64);
        val[nt] = p + b2n;
      }
    } else {
#pragma unroll
      for (int nt = 0; nt < 4; ++nt) val[nt] = xc[nt];
    }

    // insert val (fp16) at k=n_cur: wave-uniform selects
    const int sn = n_cur >> 5;
    const int en2 = (n_cur >> 1) & 3;
    const int gn = (n_cur >> 3) & 3;
    const int hin = n_cur & 1;
    const bool own = (g == gn);
    ushort_t hv[4];
#pragma unroll
    for (int nt = 0; nt < 4; ++nt) hv[nt] = __half_as_ushort(__float2half_rn(val[nt]));
#pragma unroll
    for (int S = 0; S < 4; ++S) {
      if (S != sn) continue;    // uniform
#pragma unroll
      for (int nt = 0; nt < 4; ++nt) {
        uint4& Bq = breg[nt][S];
        uint hvn = (uint)hv[nt];
        if (en2 == 0) {
          uint old = Bq.x;
          uint nw = hin ? ((old & 0x0000FFFFu) | (hvn << 16)) : ((old & 0xFFFF0000u) | hvn);
          Bq.x = own ? nw : old;
        } else if (en2 == 1) {
          uint old = Bq.y;
          uint nw = hin ? ((old & 0x0000FFFFu) | (hvn << 16)) : ((old & 0xFFFF0000u) | hvn);
          Bq.y = own ? nw : old;
        } else if (en2 == 2) {
          uint old = Bq.z;
          uint nw = hin ? ((old & 0x0000FFFFu) | (hvn << 16)) : ((old & 0xFFFF0000u) | hvn);
          Bq.z = own ? nw : old;
        } else {
          uint old = Bq.w;
          uint nw = hin ? ((old & 0x0000FFFFu) | (hvn << 16)) : ((old & 0xFFFF0000u) | hvn);
          Bq.w = own ? nw : old;
        }
      }
    }

    n_cur = n_p1; n_p1 = n_p2; n_p2 = n_p3;
#pragma unroll
    for (int nt = 0; nt < 4; ++nt) xc[nt] = xn[nt];
  }

  // ---- output: per-wave 64-row LDS transpose chunks (tbuf @ smem base)
  __syncthreads();   // drain tail DMA before overwriting stage area
  ushort_t* tbuf = (ushort_t*)smem;   // 64*132 halfs = 16896B
  for (int c = 0; c < 8; ++c) {
    __syncthreads();
    if (w == c) {
#pragma unroll
      for (int nt = 0; nt < 4; ++nt) {
        int r = nt * 16 + n16;
#pragma unroll
        for (int S = 0; S < 4; ++S) {
          int k = 32 * S + 8 * g;
          *(uint2*)&tbuf[r * 132 + k] = make_uint2(breg[nt][S].x, breg[nt][S].y);
          *(uint2*)&tbuf[r * 132 + k + 4] = make_uint2(breg[nt][S].z, breg[nt][S].w);
        }
      }
    }
    __syncthreads();
    const size_t obase = ((size_t)d * BB + bx * 512 + c * 64) * NN;
    for (int idx = tid; idx < 64 * NN; idx += TPB) {
      int rl = idx / NN;
      int col = idx - rl * NN;
      out[obase + idx] = __half2float(__ushort_as_half(tbuf[rl * 132 + col]));
    }
  }
}

// ======================= variant B (R4 fallback, verbatim) =======================
__global__ void prep_w1a(const float* __restrict__ W1, ushort_t* __restrict__ W1A) {
  int idx = blockIdx.x * 256 + threadIdx.x;
  int node = idx >> 12;
  int rem = idx & 4095;
  int j = rem >> 7;
  int k = rem & 127;
  float v = (k < NN) ? W1[((size_t)node * HH + j) * (NN + 1) + k] : 0.f;
  int t = (j * KP + k) ^ ((j & 7) << 3);
  W1A[(size_t)node * 4096 + t] = __half_as_ushort(__float2half_rn(v));
}

__global__ void prep_mexp(const float* __restrict__ A, ushort_t* __restrict__ mexp) {
  int idx = blockIdx.x * 256 + threadIdx.x;
  int d = idx / 12800;
  int rem = idx - d * 12800;
  int node = rem >> 7;
  int k = rem & 127;
  ushort_t v = 0u;
  if (k < NN) v = (A[((size_t)d * NN + k) * NN + node] != 0.f) ? 0xFFFFu : 0u;
  mexp[idx] = v;
}

__global__ void prep_epi(const float* __restrict__ b1, const float* __restrict__ W2,
                         const float* __restrict__ W1, const float* __restrict__ b2,
                         float* __restrict__ epi) {
  int idx = blockIdx.x * 256 + threadIdx.x;
  if (idx >= NN * 100) return;
  int node = idx / 100;
  int c = idx - node * 100;
  float v = 0.f;
  if (c < 32) v = b1[node * HH + c];
  else if (c < 64) v = W2[node * HH + (c - 32)];
  else if (c < 96) v = W1[((size_t)node * HH + (c - 64)) * (NN + 1) + NN];
  else if (c == 96) v = b2[node];
  epi[idx] = v;
}

#define EPI_OFF 0
#define MEXP_OFF 40000
#define STAGE_OFF 65600
#define SMEM_BYTES 81984

__global__ __launch_bounds__(TPB, 2) void dag_mfma(
    const float* __restrict__ xT, const int* __restrict__ order,
    const int* __restrict__ do_idx_p, const ushort_t* __restrict__ W1A,
    const ushort_t* __restrict__ mexp_g, const float* __restrict__ epi_g,
    float* __restrict__ out)
{
  __shared__ __align__(16) char smem[SMEM_BYTES];
  float* epi_l = (float*)(smem + EPI_OFF);
  ushort_t* mexp_l = (ushort_t*)(smem + MEXP_OFF);
  ushort_t* stage = (ushort_t*)(smem + STAGE_OFF);

  const int d = blockIdx.y;
  const int bx = blockIdx.x;
  const int tid = threadIdx.x;
  const int w = tid >> 6;
  const int lane = tid & 63;
  const int g = lane >> 4;
  const int n16 = lane & 15;
  const int di = __builtin_amdgcn_readfirstlane(do_idx_p[0]);
  const int rowbase = bx * 512 + w * 64 + n16;

  {
    const uint4* s4 = (const uint4*)epi_g;
    uint4* d4 = (uint4*)epi_l;
    for (int i = tid; i < 2500; i += TPB) d4[i] = s4[i];
    const uint4* m4 = (const uint4*)(mexp_g + (size_t)d * NN * KP);
    uint4* md = (uint4*)mexp_l;
    for (int i = tid; i < 1600; i += TPB) md[i] = m4[i];
  }

  const int* ord = order + d * NN;
  int node = __builtin_amdgcn_readfirstlane(ord[0]);

  {
    const ushort_t* gsrc = W1A + (size_t)node * 4096 + tid * 8;
    ushort_t* ldst = stage + (w << 9);
    __builtin_amdgcn_global_load_lds((const AS_GLOBAL void*)gsrc,
                                     (AS_LDS void*)ldst, 16, 0, 0);
  }

  float xv[4];
  {
    const float* xp = xT + (size_t)node * BB + rowbase;
#pragma unroll
    for (int nt = 0; nt < 4; ++nt) xv[nt] = xp[nt * 16];
  }

  uint4 breg[4][4];
#pragma unroll
  for (int nt = 0; nt < 4; ++nt)
#pragma unroll
    for (int S = 0; S < 4; ++S) breg[nt][S] = make_uint4(0u, 0u, 0u, 0u);

  __syncthreads();

  int cur = 0;
#pragma unroll 1
  for (int step = 0; step < NN; ++step) {
    const int node_next =
        __builtin_amdgcn_readfirstlane(ord[(step < NN - 1) ? step + 1 : step]);
    {
      const ushort_t* gsrc = W1A + (size_t)node_next * 4096 + tid * 8;
      ushort_t* ldst = stage + ((cur ^ 1) << 12) + (w << 9);
      __builtin_amdgcn_global_load_lds((const AS_GLOBAL void*)gsrc,
                                       (AS_LDS void*)ldst, 16, 0, 0);
    }
    float xn[4];
    {
      const float* xp = xT + (size_t)node_next * BB + rowbase;
#pragma unroll
      for (int nt = 0; nt < 4; ++nt) xn[nt] = xp[nt * 16];
    }

    float val[4];
    if (node != di) {
      const float* ep = epi_l + node * 100;
      const float4 b1a = *(const float4*)(ep + 4 * g);
      const float4 b1b = *(const float4*)(ep + 16 + 4 * g);
      const float4 w2a = *(const float4*)(ep + 32 + 4 * g);
      const float4 w2b = *(const float4*)(ep + 48 + 4 * g);
      const float4 wxa = *(const float4*)(ep + 64 + 4 * g);
      const float4 wxb = *(const float4*)(ep + 80 + 4 * g);
      const float b2n = ep[96];

      f32x4 acc[4][2];
#pragma unroll
      for (int nt = 0; nt < 4; ++nt) {
        acc[nt][0] = (f32x4){b1a.x, b1a.y, b1a.z, b1a.w};
        acc[nt][1] = (f32x4){b1b.x, b1b.y, b1b.z, b1b.w};
      }

      const ushort_t* sb = stage + (cur << 12);
      const ushort_t* mb = mexp_l + node * KP;

      __builtin_amdgcn_s_setprio(1);
#pragma unroll
      for (int S = 0; S < 4; ++S) {
        const int koff = 32 * S + 8 * g;
        const int h0 = (n16 * KP + koff) ^ ((n16 & 7) << 3);
        const int h1 = ((16 + n16) * KP + koff) ^ ((n16 & 7) << 3);
        FU a0, a1, mk;
        a0.u = *(const uint4*)(sb + h0);
        a1.u = *(const uint4*)(sb + h1);
        mk.u = *(const uint4*)(mb + koff);
        a0.u.x &= mk.u.x; a0.u.y &= mk.u.y; a0.u.z &= mk.u.z; a0.u.w &= mk.u.w;
        a1.u.x &= mk.u.x; a1.u.y &= mk.u.y; a1.u.z &= mk.u.z; a1.u.w &= mk.u.w;
#pragma unroll
        for (int nt = 0; nt < 4; ++nt) {
          FU bu; bu.u = breg[nt][S];
          acc[nt][0] = __builtin_amdgcn_mfma_f32_16x16x32_f16(a0.h, bu.h, acc[nt][0], 0, 0, 0);
          acc[nt][1] = __builtin_amdgcn_mfma_f32_16x16x32_f16(a1.h, bu.h, acc[nt][1], 0, 0, 0);
        }
      }
      __builtin_amdgcn_s_setprio(0);

      const float wa[4] = {w2a.x, w2a.y, w2a.z, w2a.w};
      const float wbv[4] = {w2b.x, w2b.y, w2b.z, w2b.w};
      const float xa[4] = {wxa.x, wxa.y, wxa.z, wxa.w};
      const float xb[4] = {wxb.x, wxb.y, wxb.z, wxb.w};
#pragma unroll
      for (int nt = 0; nt < 4; ++nt) {
        float p = 0.f;
#pragma unroll
        for (int r4 = 0; r4 < 4; ++r4) {
          float h0 = fmaf(xa[r4], xv[nt], acc[nt][0][r4]);
          h0 = fmaxf(h0, 0.01f * h0);
          p = fmaf(wa[r4], h0, p);
          float h1 = fmaf(xb[r4], xv[nt], acc[nt][1][r4]);
          h1 = fmaxf(h1, 0.01f * h1);
          p = fmaf(wbv[r4], h1, p);
        }
        p += __shfl_xor(p, 16, 64);
        p += __shfl_xor(p, 32, 64);
        val[nt] = p + b2n;
      }
    } else {
#pragma unroll
      for (int nt = 0; nt < 4; ++nt) val[nt] = xv[nt];
    }

    const int sn = node >> 5;
    const int en2 = (node >> 1) & 3;
    const int gn = (node >> 3) & 3;
    const int hin = node & 1;
    const bool own = (g == gn);
    ushort_t hv[4];
#pragma unroll
    for (int nt = 0; nt < 4; ++nt) hv[nt] = __half_as_ushort(__float2half_rn(val[nt]));
#pragma unroll
    for (int S = 0; S < 4; ++S) {
      if (S != sn) continue;
#pragma unroll
      for (int nt = 0; nt < 4; ++nt) {
        uint4& Bq = breg[nt][S];
        uint hvn = (uint)hv[nt];
        if (en2 == 0) {
          uint old = Bq.x;
          uint nw = hin ? ((old & 0x0000FFFFu) | (hvn << 16)) : ((old & 0xFFFF0000u) | hvn);
          Bq.x = own ? nw : old;
        } else if (en2 == 1) {
          uint old = Bq.y;
          uint nw = hin ? ((old & 0x0000FFFFu) | (hvn << 16)) : ((old & 0xFFFF0000u) | hvn);
          Bq.y = own ? nw : old;
        } else if (en2 == 2) {
          uint old = Bq.z;
          uint nw = hin ? ((old & 0x0000FFFFu) | (hvn << 16)) : ((old & 0xFFFF0000u) | hvn);
          Bq.z = own ? nw : old;
        } else {
          uint old = Bq.w;
          uint nw = hin ? ((old & 0x0000FFFFu) | (hvn << 16)) : ((old & 0xFFFF0000u) | hvn);
          Bq.w = own ? nw : old;
        }
      }
    }

    __syncthreads();
    cur ^= 1;
    node = node_next;
#pragma unroll
    for (int nt = 0; nt < 4; ++nt) xv[nt] = xn[nt];
  }

  ushort_t* tbuf = (ushort_t*)(smem + MEXP_OFF);
  for (int c = 0; c < 8; ++c) {
    __syncthreads();
    if (w == c) {
#pragma unroll
      for (int nt = 0; nt < 4; ++nt) {
        int r = nt * 16 + n16;
#pragma unroll
        for (int S = 0; S < 4; ++S) {
          int k = 32 * S + 8 * g;
          *(uint2*)&tbuf[r * 132 + k] = make_uint2(breg[nt][S].x, breg[nt][S].y);
          *(uint2*)&tbuf[r * 132 + k + 4] = make_uint2(breg[nt][S].z, breg[nt][S].w);
        }
      }
    }
    __syncthreads();
    const size_t obase = ((size_t)d * BB + bx * 512 + c * 64) * NN;
    for (int idx = tid; idx < 64 * NN; idx += TPB) {
      int rl = idx / NN;
      int col = idx - rl * NN;
      out[obase + idx] = __half2float(__ushort_as_half(tbuf[rl * 132 + col]));
    }
  }
}

// ======================= launch =======================
extern "C" void kernel_launch(void* const* d_in, const int* in_sizes, int n_in,
                              void* d_out, int out_size, void* d_ws, size_t ws_size,
                              hipStream_t stream) {
  const float* x     = (const float*)d_in[0];
  const float* A     = (const float*)d_in[1];
  const int* order   = (const int*)d_in[2];
  const int* do_idx  = (const int*)d_in[3];
  const float* W1    = (const float*)d_in[4];
  const float* b1    = (const float*)d_in[5];
  const float* W2    = (const float*)d_in[6];
  const float* b2    = (const float*)d_in[7];
  float* out = (float*)d_out;

  char* ws = (char*)d_ws;
  const size_t XT_B = 3276800UL;                 // 8192*100*4
  const size_t W1M_B = (size_t)DD * NN * 4096 * 2;  // 26,214,400
  const size_t NEED_A = XT_B + W1M_B + NN * 36 * 4; // 29,505,600

  if (ws_size >= NEED_A) {
    float* xT     = (float*)ws;
    ushort_t* W1M = (ushort_t*)(ws + XT_B);
    float* epi    = (float*)(ws + XT_B + W1M_B);
    hipLaunchKernelGGL(prep_xt, dim3((BB * NN) / 256), dim3(256), 0, stream, x, xT);
    hipLaunchKernelGGL(prep_w1m, dim3((DD * NN * 4096) / 256), dim3(256), 0, stream,
                       A, W1, b1, W1M);
    hipLaunchKernelGGL(prep_epi2, dim3((NN * 36 + 255) / 256), dim3(256), 0, stream,
                       W2, b2, epi);
    hipLaunchKernelGGL(dag_mfma_pm, dim3(BB / 512, DD), dim3(TPB), 0, stream,
                       xT, order, do_idx, W1M, epi, out);
  } else {
    float* xT       = (float*)ws;
    ushort_t* W1A   = (ushort_t*)(ws + 3276800);
    ushort_t* mexp  = (ushort_t*)(ws + 3276800 + 819200);
    float* epi      = (float*)(ws + 3276800 + 819200 + 819200);
    hipLaunchKernelGGL(prep_xt, dim3((BB * NN) / 256), dim3(256), 0, stream, x, xT);
    hipLaunchKernelGGL(prep_w1a, dim3(1600), dim3(256), 0, stream, W1, W1A);
    hipLaunchKernelGGL(prep_mexp, dim3(1600), dim3(256), 0, stream, A, mexp);
    hipLaunchKernelGGL(prep_epi, dim3((NN * 100 + 255) / 256), dim3(256), 0, stream,
                       b1, W2, W1, b2, epi);
    hipLaunchKernelGGL(dag_mfma, dim3(BB / 512, DD), dim3(TPB), 0, stream,
                       xT, order, do_idx, W1A, mexp, epi, out);
  }
}

// Round 7
// 305.584 us; speedup vs baseline: 3.0745x; 1.0868x over previous
//
#include <hip/hip_runtime.h>
#include <hip/hip_fp16.h>

#define NN 100   // nodes
#define HH 32    // hidden
#define BB 8192  // batch
#define DD 32    // dags
#define KP 128   // padded K
#define TPB 512  // 8 waves per block

typedef _Float16 f16x8 __attribute__((ext_vector_type(8)));
typedef _Float16 f16x2 __attribute__((ext_vector_type(2)));
typedef __fp16 fph2 __attribute__((ext_vector_type(2)));
typedef float f32x4 __attribute__((ext_vector_type(4)));
typedef unsigned short ushort_t;
typedef unsigned int uint_t;
union FU { uint4 u; f16x8 h; };
union PU { fph2 p; f16x2 h; uint_t u; };

#define AS_GLOBAL __attribute__((address_space(1)))
#define AS_LDS    __attribute__((address_space(3)))

// ======================= prep =======================
__global__ void prep_xt(const float* __restrict__ x, float* __restrict__ xT) {
  int idx = blockIdx.x * 256 + threadIdx.x;
  if (idx >= BB * NN) return;
  int b = idx & (BB - 1);
  int n = idx >> 13;
  xT[idx] = x[(size_t)b * NN + n];
}

// W1M[d][node]: 32x128 fp16 tile, swizzled (j*128+k)^((j&7)<<3)
// k<100: mask*W1; k==100: x-weight; k==101: b1; else 0
__global__ void prep_w1m(const float* __restrict__ A, const float* __restrict__ W1,
                         const float* __restrict__ b1, ushort_t* __restrict__ W1M) {
  int idx = blockIdx.x * 256 + threadIdx.x;   // DD*NN*4096
  int tile = idx >> 12;
  int d = tile / NN;
  int node = tile - d * NN;
  int rem = idx & 4095;
  int j = rem >> 7;
  int k = rem & 127;
  float v = 0.f;
  if (k < NN) {
    float m = A[((size_t)d * NN + k) * NN + node];
    v = (m != 0.f) ? W1[((size_t)node * HH + j) * (NN + 1) + k] : 0.f;
  } else if (k == NN) {
    v = W1[((size_t)node * HH + j) * (NN + 1) + NN];
  } else if (k == NN + 1) {
    v = b1[node * HH + j];
  }
  int t = (j * KP + k) ^ ((j & 7) << 3);
  W1M[(size_t)tile * 4096 + t] = __half_as_ushort(__float2half_rn(v));
}

// epi3[node][20] uints: 0..15 = half2(W2[2c],W2[2c+1]); 16 = b2 bits; 17..19 pad
__global__ void prep_epi3(const float* __restrict__ W2, const float* __restrict__ b2,
                          uint_t* __restrict__ epi) {
  int idx = blockIdx.x * 256 + threadIdx.x;
  if (idx >= NN * 20) return;
  int node = idx / 20;
  int c = idx - node * 20;
  uint_t v = 0u;
  if (c < 16) {
    uint_t lo = __half_as_ushort(__float2half_rn(W2[node * HH + 2 * c]));
    uint_t hi = __half_as_ushort(__float2half_rn(W2[node * HH + 2 * c + 1]));
    v = lo | (hi << 16);
  } else if (c == 16) {
    v = __float_as_uint(b2[node]);
  }
  epi[idx] = v;
}

// ======================= main =======================
// LDS: stage 2 sets x 4 tiles x 8192B = 65536; epi 8000B @65536; total 73536
#define EPI_OFF 65536
#define SMEM_BYTES (65536 + 8000)

__global__ __launch_bounds__(TPB, 4) void dag_mfma_ss(
    const float* __restrict__ xT,      // [N][B]
    const int* __restrict__ order,     // [D][N]
    const int* __restrict__ do_idx_p,  // [1]
    const ushort_t* __restrict__ W1M,  // [D][N][4096] fp16 swizzled
    const uint_t* __restrict__ epi_g,  // [N][20]
    float* __restrict__ out)           // [D][B][N]
{
  __shared__ __align__(16) char smem[SMEM_BYTES];
  ushort_t* stage = (ushort_t*)smem;
  const char* sp = (const char*)smem;
  uint_t* epi_l = (uint_t*)(smem + EPI_OFF);

  const int d = blockIdx.y;
  const int bx = blockIdx.x;
  const int tid = threadIdx.x;
  const int w = tid >> 6;
  const int lane = tid & 63;
  const int g = lane >> 4;
  const int n16 = lane & 15;
  const int di = __builtin_amdgcn_readfirstlane(do_idx_p[0]);
  const int rowbase = bx * 512 + w * 64 + n16;

  // epi preload (500 uint4)
  {
    const uint4* s4 = (const uint4*)epi_g;
    uint4* d4 = (uint4*)epi_l;
    for (int i = tid; i < 500; i += TPB) d4[i] = s4[i];
  }

  const ushort_t* Wd = W1M + (size_t)d * NN * 4096;
  const int* ord = order + d * NN;

  // per-lane swizzled ds_read byte offsets (within a tile), per S
  int vs[4];
#pragma unroll
  for (int S = 0; S < 4; ++S) {
    int hw = n16 * 128 + ((8 * g) ^ ((n16 & 3) << 3)) + 32 * (S ^ ((n16 >> 2) & 1));
    vs[S] = 2 * hw + 32768;   // +32768: loop-top XOR flips to set0 first
  }

  // nodes + stage + x for superstep 0
  int nd[4], nn[4];
#pragma unroll
  for (int q = 0; q < 4; ++q) nd[q] = __builtin_amdgcn_readfirstlane(ord[q]);
#pragma unroll
  for (int q = 0; q < 4; ++q) {
    const ushort_t* gsrc = Wd + (size_t)nd[q] * 4096 + tid * 8;
    __builtin_amdgcn_global_load_lds((const AS_GLOBAL void*)gsrc,
        (AS_LDS void*)(stage + q * 4096 + (w << 9)), 16, 0, 0);
  }
  float xq[4][4];
#pragma unroll
  for (int q = 0; q < 4; ++q) {
    const float* xp = xT + (size_t)nd[q] * BB + rowbase;
#pragma unroll
    for (int nt = 0; nt < 4; ++nt) xq[q][nt] = xp[nt * 16];
  }

  // B-operand: breg[nt][S]: lane(g,n16) holds k=32S+8g+{0..7}, row rowbase+16nt
  // k=101 (S=3 .z hi, g==0) = 1.0 (b1 row); k=100 (.z lo) = per-step x
  uint4 breg[4][4];
#pragma unroll
  for (int nt = 0; nt < 4; ++nt) {
#pragma unroll
    for (int S = 0; S < 4; ++S) breg[nt][S] = make_uint4(0u, 0u, 0u, 0u);
    breg[nt][3].z = (g == 0) ? 0x3C000000u : 0u;
  }

  const f32x4 zero4 = {0.f, 0.f, 0.f, 0.f};
  PU c001; c001.u = 0x211F211Fu;   // fp16 0.01 x2

#pragma unroll 1
  for (int ss = 0; ss < 25; ++ss) {
    // superstep top: everything outstanding is exactly what we need
    asm volatile("s_waitcnt vmcnt(0) lgkmcnt(0)" ::: "memory");
    __builtin_amdgcn_s_barrier();
    __builtin_amdgcn_sched_barrier(0);

#pragma unroll
    for (int S = 0; S < 4; ++S) vs[S] ^= 32768;   // toggle set

    const bool more = (ss < 24);
    if (more) {
      // issue next superstep's tiles into the other set
#pragma unroll
      for (int q = 0; q < 4; ++q)
        nn[q] = __builtin_amdgcn_readfirstlane(ord[4 * (ss + 1) + q]);
      const int dsts = (((ss + 1) & 1) << 14);   // halfword offset of set
#pragma unroll
      for (int q = 0; q < 4; ++q) {
        const ushort_t* gsrc = Wd + (size_t)nn[q] * 4096 + tid * 8;
        __builtin_amdgcn_global_load_lds((const AS_GLOBAL void*)gsrc,
            (AS_LDS void*)(stage + dsts + q * 4096 + (w << 9)), 16, 0, 0);
      }
    }

    // ---- 4 steps, barrier-free
#pragma unroll
    for (int q = 0; q < 4; ++q) {
      const int node = nd[q];

      // insert x at k=100 (S=3 .z lo, owner g==0)
#pragma unroll
      for (int nt = 0; nt < 4; ++nt) {
        uint_t old = breg[nt][3].z;
        uint_t ins = (old & 0xFFFF0000u) |
                     (uint_t)__half_as_ushort(__float2half_rn(xq[q][nt]));
        breg[nt][3].z = (g == 0) ? ins : old;
      }

      float val[4];
      if (node != di) {
        const char* ep = (const char*)epi_l + node * 80;
        const uint2 wlo = *(const uint2*)(ep + 8 * g);        // j=4g..4g+3
        const uint2 whi = *(const uint2*)(ep + 32 + 8 * g);   // j=16+4g..
        const float b2n = *(const float*)(ep + 64);

        f32x4 acc[4][2];
        __builtin_amdgcn_s_setprio(1);
#pragma unroll
        for (int S = 0; S < 4; ++S) {
          FU a0, a1;
          a0.u = *(const uint4*)(sp + vs[S] + q * 8192);
          a1.u = *(const uint4*)(sp + vs[S] + q * 8192 + 4096);
#pragma unroll
          for (int nt = 0; nt < 4; ++nt) {
            FU bu; bu.u = breg[nt][S];
            if (S == 0) {
              acc[nt][0] = __builtin_amdgcn_mfma_f32_16x16x32_f16(a0.h, bu.h, zero4, 0, 0, 0);
              acc[nt][1] = __builtin_amdgcn_mfma_f32_16x16x32_f16(a1.h, bu.h, zero4, 0, 0, 0);
            } else {
              acc[nt][0] = __builtin_amdgcn_mfma_f32_16x16x32_f16(a0.h, bu.h, acc[nt][0], 0, 0, 0);
              acc[nt][1] = __builtin_amdgcn_mfma_f32_16x16x32_f16(a1.h, bu.h, acc[nt][1], 0, 0, 0);
            }
          }
        }
        __builtin_amdgcn_s_setprio(0);

        PU w01, w23, w45, w67;
        w01.u = wlo.x; w23.u = wlo.y; w45.u = whi.x; w67.u = whi.y;
#pragma unroll
        for (int nt = 0; nt < 4; ++nt) {
#if __has_builtin(__builtin_amdgcn_fdot2)
          PU h01, h23, h45, h67;
          h01.p = __builtin_amdgcn_cvt_pkrtz(acc[nt][0][0], acc[nt][0][1]);
          h23.p = __builtin_amdgcn_cvt_pkrtz(acc[nt][0][2], acc[nt][0][3]);
          h45.p = __builtin_amdgcn_cvt_pkrtz(acc[nt][1][0], acc[nt][1][1]);
          h67.p = __builtin_amdgcn_cvt_pkrtz(acc[nt][1][2], acc[nt][1][3]);
          h01.p = __builtin_elementwise_max(h01.p, h01.p * c001.p);
          h23.p = __builtin_elementwise_max(h23.p, h23.p * c001.p);
          h45.p = __builtin_elementwise_max(h45.p, h45.p * c001.p);
          h67.p = __builtin_elementwise_max(h67.p, h67.p * c001.p);
          float p = __builtin_amdgcn_fdot2(h01.h, w01.h, 0.f, false);
          p = __builtin_amdgcn_fdot2(h23.h, w23.h, p, false);
          p = __builtin_amdgcn_fdot2(h45.h, w45.h, p, false);
          p = __builtin_amdgcn_fdot2(h67.h, w67.h, p, false);
#else
          float p = 0.f;
          const uint_t wu0[2] = {w01.u, w23.u};
          const uint_t wu1[2] = {w45.u, w67.u};
#pragma unroll
          for (int r4 = 0; r4 < 4; ++r4) {
            float wv0 = __half2float(__ushort_as_half(
                (ushort_t)((wu0[r4 >> 1] >> ((r4 & 1) * 16)) & 0xFFFFu)));
            float wv1 = __half2float(__ushort_as_half(
                (ushort_t)((wu1[r4 >> 1] >> ((r4 & 1) * 16)) & 0xFFFFu)));
            float h0 = acc[nt][0][r4]; h0 = fmaxf(h0, 0.01f * h0);
            float h1 = acc[nt][1][r4]; h1 = fmaxf(h1, 0.01f * h1);
            p = fmaf(wv0, h0, p);
            p = fmaf(wv1, h1, p);
          }
#endif
          p += __shfl_xor(p, 16, 64);
          p += __shfl_xor(p, 32, 64);
          val[nt] = p + b2n;
        }
      } else {
#pragma unroll
        for (int nt = 0; nt < 4; ++nt) val[nt] = xq[q][nt];
      }

      // refill xq[q] for next superstep (after consumption)
      if (more) {
        const float* xp = xT + (size_t)nn[q] * BB + rowbase;
#pragma unroll
        for (int nt = 0; nt < 4; ++nt) xq[q][nt] = xp[nt * 16];
      }

      // insert val (fp16) at k=node: wave-uniform selects
      const int sn = node >> 5;
      const int en2 = (node >> 1) & 3;
      const int gn = (node >> 3) & 3;
      const int hin = node & 1;
      const bool own = (g == gn);
      ushort_t hv[4];
#pragma unroll
      for (int nt = 0; nt < 4; ++nt) hv[nt] = __half_as_ushort(__float2half_rn(val[nt]));
#pragma unroll
      for (int S = 0; S < 4; ++S) {
        if (S != sn) continue;    // uniform
#pragma unroll
        for (int nt = 0; nt < 4; ++nt) {
          uint4& Bq = breg[nt][S];
          uint_t hvn = (uint_t)hv[nt];
          if (en2 == 0) {
            uint_t old = Bq.x;
            uint_t nw = hin ? ((old & 0x0000FFFFu) | (hvn << 16)) : ((old & 0xFFFF0000u) | hvn);
            Bq.x = own ? nw : old;
          } else if (en2 == 1) {
            uint_t old = Bq.y;
            uint_t nw = hin ? ((old & 0x0000FFFFu) | (hvn << 16)) : ((old & 0xFFFF0000u) | hvn);
            Bq.y = own ? nw : old;
          } else if (en2 == 2) {
            uint_t old = Bq.z;
            uint_t nw = hin ? ((old & 0x0000FFFFu) | (hvn << 16)) : ((old & 0xFFFF0000u) | hvn);
            Bq.z = own ? nw : old;
          } else {
            uint_t old = Bq.w;
            uint_t nw = hin ? ((old & 0x0000FFFFu) | (hvn << 16)) : ((old & 0xFFFF0000u) | hvn);
            Bq.w = own ? nw : old;
          }
        }
      }
    }

#pragma unroll
    for (int q = 0; q < 4; ++q) nd[q] = nn[q];
  }

  // ---- output: per-wave 64-row LDS transpose chunks (tbuf @ smem base, set0)
  ushort_t* tbuf = (ushort_t*)smem;   // 64*132 halfs = 16896B
  for (int c = 0; c < 8; ++c) {
    __syncthreads();
    if (w == c) {
#pragma unroll
      for (int nt = 0; nt < 4; ++nt) {
        int r = nt * 16 + n16;
#pragma unroll
        for (int S = 0; S < 4; ++S) {
          int k = 32 * S + 8 * g;
          *(uint2*)&tbuf[r * 132 + k] = make_uint2(breg[nt][S].x, breg[nt][S].y);
          *(uint2*)&tbuf[r * 132 + k + 4] = make_uint2(breg[nt][S].z, breg[nt][S].w);
        }
      }
    }
    __syncthreads();
    const size_t obase = ((size_t)d * BB + bx * 512 + c * 64) * NN;
    for (int idx = tid; idx < 64 * NN; idx += TPB) {
      int rl = idx / NN;
      int col = idx - rl * NN;
      out[obase + idx] = __half2float(__ushort_as_half(tbuf[rl * 132 + col]));
    }
  }
}

// ======================= launch =======================
extern "C" void kernel_launch(void* const* d_in, const int* in_sizes, int n_in,
                              void* d_out, int out_size, void* d_ws, size_t ws_size,
                              hipStream_t stream) {
  const float* x     = (const float*)d_in[0];
  const float* A     = (const float*)d_in[1];
  const int* order   = (const int*)d_in[2];
  const int* do_idx  = (const int*)d_in[3];
  const float* W1    = (const float*)d_in[4];
  const float* b1    = (const float*)d_in[5];
  const float* W2    = (const float*)d_in[6];
  const float* b2    = (const float*)d_in[7];
  float* out = (float*)d_out;

  char* ws = (char*)d_ws;
  const size_t XT_B = 3276800UL;                    // 8192*100*4
  const size_t W1M_B = (size_t)DD * NN * 4096 * 2;  // 26,214,400
  float* xT     = (float*)ws;
  ushort_t* W1M = (ushort_t*)(ws + XT_B);
  uint_t* epi   = (uint_t*)(ws + XT_B + W1M_B);     // 8000 B

  hipLaunchKernelGGL(prep_xt, dim3((BB * NN) / 256), dim3(256), 0, stream, x, xT);
  hipLaunchKernelGGL(prep_w1m, dim3((DD * NN * 4096) / 256), dim3(256), 0, stream,
                     A, W1, b1, W1M);
  hipLaunchKernelGGL(prep_epi3, dim3((NN * 20 + 255) / 256), dim3(256), 0, stream,
                     W2, b2, epi);
  hipLaunchKernelGGL(dag_mfma_ss, dim3(BB / 512, DD), dim3(TPB), 0, stream,
                     xT, order, do_idx, W1M, epi, out);
}

// Round 8
// 274.952 us; speedup vs baseline: 3.4171x; 1.1114x over previous
//
#include <hip/hip_runtime.h>
#include <hip/hip_fp16.h>

#define NN 100   // nodes
#define HH 32    // hidden
#define BB 8192  // batch
#define DD 32    // dags
#define KP 128   // padded K
#define TPB 512  // 8 waves per block

typedef _Float16 f16x8 __attribute__((ext_vector_type(8)));
typedef _Float16 f16x2 __attribute__((ext_vector_type(2)));
typedef __fp16 fph2 __attribute__((ext_vector_type(2)));
typedef float f32x4 __attribute__((ext_vector_type(4)));
typedef unsigned short ushort_t;
typedef unsigned int uint_t;
union FU { uint4 u; f16x8 h; };
union PU { fph2 p; f16x2 h; uint_t u; };

#define AS_GLOBAL __attribute__((address_space(1)))
#define AS_LDS    __attribute__((address_space(3)))

// ======================= prep =======================
// x (B,N) f32 -> xTh (N,B) fp16
__global__ void prep_xth(const float* __restrict__ x, ushort_t* __restrict__ xTh) {
  int idx = blockIdx.x * 256 + threadIdx.x;
  if (idx >= BB * NN) return;
  int b = idx & (BB - 1);
  int n = idx >> 13;
  xTh[idx] = __half_as_ushort(__float2half_rn(x[(size_t)b * NN + n]));
}

// W1M[d][node]: 32x128 fp16 tile, swizzled (j*128+k)^((j&7)<<3)
// k<100: mask*W1; k==100: x-weight; k==101: b1; else 0
__global__ void prep_w1m(const float* __restrict__ A, const float* __restrict__ W1,
                         const float* __restrict__ b1, ushort_t* __restrict__ W1M) {
  int idx = blockIdx.x * 256 + threadIdx.x;   // DD*NN*4096
  int tile = idx >> 12;
  int d = tile / NN;
  int node = tile - d * NN;
  int rem = idx & 4095;
  int j = rem >> 7;
  int k = rem & 127;
  float v = 0.f;
  if (k < NN) {
    float m = A[((size_t)d * NN + k) * NN + node];
    v = (m != 0.f) ? W1[((size_t)node * HH + j) * (NN + 1) + k] : 0.f;
  } else if (k == NN) {
    v = W1[((size_t)node * HH + j) * (NN + 1) + NN];
  } else if (k == NN + 1) {
    v = b1[node * HH + j];
  }
  int t = (j * KP + k) ^ ((j & 7) << 3);
  W1M[(size_t)tile * 4096 + t] = __half_as_ushort(__float2half_rn(v));
}

// epi3[node][20] uints: 0..15 = half2(W2[2c],W2[2c+1]); 16 = b2 bits; 17..19 pad
__global__ void prep_epi3(const float* __restrict__ W2, const float* __restrict__ b2,
                          uint_t* __restrict__ epi) {
  int idx = blockIdx.x * 256 + threadIdx.x;
  if (idx >= NN * 20) return;
  int node = idx / 20;
  int c = idx - node * 20;
  uint_t v = 0u;
  if (c < 16) {
    uint_t lo = __half_as_ushort(__float2half_rn(W2[node * HH + 2 * c]));
    uint_t hi = __half_as_ushort(__float2half_rn(W2[node * HH + 2 * c + 1]));
    v = lo | (hi << 16);
  } else if (c == 16) {
    v = __float_as_uint(b2[node]);
  }
  epi[idx] = v;
}

// ======================= main =======================
// LDS: tiles 2 sets x 4 x 8192B = 65536 @0; xstage 2 sets x 4096B @65536;
// epi 8000B @73728; total 81728 (<= 81920 -> 2 blocks/CU)
#define XS_OFF 65536
#define EPI_OFF 73728
#define SMEM_BYTES (73728 + 8000)

__global__ __launch_bounds__(TPB, 4) void dag_mfma_ss(
    const ushort_t* __restrict__ xTh,  // [N][B] fp16
    const int* __restrict__ order,     // [D][N]
    const int* __restrict__ do_idx_p,  // [1]
    const ushort_t* __restrict__ W1M,  // [D][N][4096] fp16 swizzled
    const uint_t* __restrict__ epi_g,  // [N][20]
    float* __restrict__ out)           // [D][B][N]
{
  __shared__ __align__(16) char smem[SMEM_BYTES];
  ushort_t* stage = (ushort_t*)smem;
  const char* sp = (const char*)smem;
  uint_t* epi_l = (uint_t*)(smem + EPI_OFF);

  const int d = blockIdx.y;
  const int bx = blockIdx.x;
  const int tid = threadIdx.x;
  const int w = tid >> 6;
  const int lane = tid & 63;
  const int g = lane >> 4;
  const int n16 = lane & 15;
  const int di = __builtin_amdgcn_readfirstlane(do_idx_p[0]);

  // epi preload (500 uint4)
  {
    const uint4* s4 = (const uint4*)epi_g;
    uint4* d4 = (uint4*)epi_l;
    for (int i = tid; i < 500; i += TPB) d4[i] = s4[i];
  }

  const ushort_t* Wd = W1M + (size_t)d * NN * 4096;
  const int* ord = order + d * NN;

  // per-lane swizzled ds_read byte offsets (within a tile), per S
  int vs[4];
#pragma unroll
  for (int S = 0; S < 4; ++S) {
    int hw = n16 * 128 + ((8 * g) ^ ((n16 & 3) << 3)) + 32 * (S ^ ((n16 >> 2) & 1));
    vs[S] = 2 * hw + 32768;   // +32768: loop-top XOR flips to set0 first
  }
  // x-stage byte base for this thread's wave rows (set-toggled alongside vs)
  int xso = XS_OFF + (w * 64 + n16) * 2 + 4096;   // + q*1024 + nt*32 at use

  // nodes + stage for superstep 0
  int nd[4], nn[4];
#pragma unroll
  for (int q = 0; q < 4; ++q) nd[q] = __builtin_amdgcn_readfirstlane(ord[q]);
#pragma unroll
  for (int q = 0; q < 4; ++q) {
    const ushort_t* gsrc = Wd + (size_t)nd[q] * 4096 + tid * 8;
    __builtin_amdgcn_global_load_lds((const AS_GLOBAL void*)gsrc,
        (AS_LDS void*)(stage + q * 4096 + (w << 9)), 16, 0, 0);
  }
#pragma unroll
  for (int q = 0; q < 4; ++q) {
    if (w == q) {   // wave-uniform; 64 lanes x 16B = 1KB column
      const ushort_t* gx = xTh + (size_t)nd[q] * BB + bx * 512 + lane * 8;
      __builtin_amdgcn_global_load_lds((const AS_GLOBAL void*)gx,
          (AS_LDS void*)(smem + XS_OFF + q * 1024), 16, 0, 0);
    }
  }

  // B-operand: breg[nt][S]: lane(g,n16) holds k=32S+8g+{0..7}, row = block
  // rows [bx*512 + w*64 + nt*16 + n16]; k=101 (S=3 .z hi, g==0) = 1.0 (b1 row)
  uint4 breg[4][4];
#pragma unroll
  for (int nt = 0; nt < 4; ++nt) {
#pragma unroll
    for (int S = 0; S < 4; ++S) breg[nt][S] = make_uint4(0u, 0u, 0u, 0u);
    breg[nt][3].z = (g == 0) ? 0x3C000000u : 0u;
  }

  const f32x4 zero4 = {0.f, 0.f, 0.f, 0.f};
  PU c001; c001.u = 0x211F211Fu;   // fp16 0.01 x2

#pragma unroll 1
  for (int ss = 0; ss < 25; ++ss) {
    // superstep top: everything outstanding is exactly what we need
    asm volatile("s_waitcnt vmcnt(0) lgkmcnt(0)" ::: "memory");
    __builtin_amdgcn_s_barrier();
    __builtin_amdgcn_sched_barrier(0);

#pragma unroll
    for (int S = 0; S < 4; ++S) vs[S] ^= 32768;   // toggle tile set
    xso ^= 4096;                                   // toggle x set

    const bool more = (ss < 24);
    if (more) {
      // issue next superstep's tiles + x columns into the other set
#pragma unroll
      for (int q = 0; q < 4; ++q)
        nn[q] = __builtin_amdgcn_readfirstlane(ord[4 * (ss + 1) + q]);
      const int dsts = (((ss + 1) & 1) << 14);   // halfword offset of tile set
#pragma unroll
      for (int q = 0; q < 4; ++q) {
        const ushort_t* gsrc = Wd + (size_t)nn[q] * 4096 + tid * 8;
        __builtin_amdgcn_global_load_lds((const AS_GLOBAL void*)gsrc,
            (AS_LDS void*)(stage + dsts + q * 4096 + (w << 9)), 16, 0, 0);
      }
      const int xdst = XS_OFF + (((ss + 1) & 1) << 12);
#pragma unroll
      for (int q = 0; q < 4; ++q) {
        if (w == q) {
          const ushort_t* gx = xTh + (size_t)nn[q] * BB + bx * 512 + lane * 8;
          __builtin_amdgcn_global_load_lds((const AS_GLOBAL void*)gx,
              (AS_LDS void*)(smem + xdst + q * 1024), 16, 0, 0);
        }
      }
    }

    // ---- 4 steps, barrier-free
#pragma unroll
    for (int q = 0; q < 4; ++q) {
      const int node = nd[q];

      // x bits for this step's 4 row-tiles (fp16, from LDS)
      ushort_t xb[4];
#pragma unroll
      for (int nt = 0; nt < 4; ++nt)
        xb[nt] = *(const ushort_t*)(sp + xso + q * 1024 + nt * 32);

      // insert x at k=100 (S=3 .z lo, owner g==0)
#pragma unroll
      for (int nt = 0; nt < 4; ++nt) {
        uint_t old = breg[nt][3].z;
        uint_t ins = (old & 0xFFFF0000u) | (uint_t)xb[nt];
        breg[nt][3].z = (g == 0) ? ins : old;
      }

      float val[4];
      if (node != di) {
        const char* ep = (const char*)epi_l + node * 80;
        const uint2 wlo = *(const uint2*)(ep + 8 * g);        // j=4g..4g+3
        const uint2 whi = *(const uint2*)(ep + 32 + 8 * g);   // j=16+4g..
        const float b2n = *(const float*)(ep + 64);

        f32x4 acc[4][2];
        __builtin_amdgcn_s_setprio(1);
#pragma unroll
        for (int S = 0; S < 4; ++S) {
          FU a0, a1;
          a0.u = *(const uint4*)(sp + vs[S] + q * 8192);
          a1.u = *(const uint4*)(sp + vs[S] + q * 8192 + 4096);
#pragma unroll
          for (int nt = 0; nt < 4; ++nt) {
            FU bu; bu.u = breg[nt][S];
            if (S == 0) {
              acc[nt][0] = __builtin_amdgcn_mfma_f32_16x16x32_f16(a0.h, bu.h, zero4, 0, 0, 0);
              acc[nt][1] = __builtin_amdgcn_mfma_f32_16x16x32_f16(a1.h, bu.h, zero4, 0, 0, 0);
            } else {
              acc[nt][0] = __builtin_amdgcn_mfma_f32_16x16x32_f16(a0.h, bu.h, acc[nt][0], 0, 0, 0);
              acc[nt][1] = __builtin_amdgcn_mfma_f32_16x16x32_f16(a1.h, bu.h, acc[nt][1], 0, 0, 0);
            }
          }
        }
        __builtin_amdgcn_s_setprio(0);

        PU w01, w23, w45, w67;
        w01.u = wlo.x; w23.u = wlo.y; w45.u = whi.x; w67.u = whi.y;
#pragma unroll
        for (int nt = 0; nt < 4; ++nt) {
          PU h01, h23, h45, h67;
          h01.p = __builtin_amdgcn_cvt_pkrtz(acc[nt][0][0], acc[nt][0][1]);
          h23.p = __builtin_amdgcn_cvt_pkrtz(acc[nt][0][2], acc[nt][0][3]);
          h45.p = __builtin_amdgcn_cvt_pkrtz(acc[nt][1][0], acc[nt][1][1]);
          h67.p = __builtin_amdgcn_cvt_pkrtz(acc[nt][1][2], acc[nt][1][3]);
          h01.p = __builtin_elementwise_max(h01.p, h01.p * c001.p);
          h23.p = __builtin_elementwise_max(h23.p, h23.p * c001.p);
          h45.p = __builtin_elementwise_max(h45.p, h45.p * c001.p);
          h67.p = __builtin_elementwise_max(h67.p, h67.p * c001.p);
          float p = __builtin_amdgcn_fdot2(h01.h, w01.h, 0.f, false);
          p = __builtin_amdgcn_fdot2(h23.h, w23.h, p, false);
          p = __builtin_amdgcn_fdot2(h45.h, w45.h, p, false);
          p = __builtin_amdgcn_fdot2(h67.h, w67.h, p, false);
          p += __shfl_xor(p, 16, 64);
          p += __shfl_xor(p, 32, 64);
          val[nt] = p + b2n;
        }
      } else {
#pragma unroll
        for (int nt = 0; nt < 4; ++nt)
          val[nt] = __half2float(__ushort_as_half(xb[nt]));
      }

      // insert val (fp16) at k=node: wave-uniform selects
      const int sn = node >> 5;
      const int en2 = (node >> 1) & 3;
      const int gn = (node >> 3) & 3;
      const int hin = node & 1;
      const bool own = (g == gn);
      ushort_t hv[4];
#pragma unroll
      for (int nt = 0; nt < 4; ++nt) hv[nt] = __half_as_ushort(__float2half_rn(val[nt]));
#pragma unroll
      for (int S = 0; S < 4; ++S) {
        if (S != sn) continue;    // uniform
#pragma unroll
        for (int nt = 0; nt < 4; ++nt) {
          uint4& Bq = breg[nt][S];
          uint_t hvn = (uint_t)hv[nt];
          if (en2 == 0) {
            uint_t old = Bq.x;
            uint_t nw = hin ? ((old & 0x0000FFFFu) | (hvn << 16)) : ((old & 0xFFFF0000u) | hvn);
            Bq.x = own ? nw : old;
          } else if (en2 == 1) {
            uint_t old = Bq.y;
            uint_t nw = hin ? ((old & 0x0000FFFFu) | (hvn << 16)) : ((old & 0xFFFF0000u) | hvn);
            Bq.y = own ? nw : old;
          } else if (en2 == 2) {
            uint_t old = Bq.z;
            uint_t nw = hin ? ((old & 0x0000FFFFu) | (hvn << 16)) : ((old & 0xFFFF0000u) | hvn);
            Bq.z = own ? nw : old;
          } else {
            uint_t old = Bq.w;
            uint_t nw = hin ? ((old & 0x0000FFFFu) | (hvn << 16)) : ((old & 0xFFFF0000u) | hvn);
            Bq.w = own ? nw : old;
          }
        }
      }
    }

#pragma unroll
    for (int q = 0; q < 4; ++q) nd[q] = nn[q];
  }

  // ---- output: per-wave 64-row LDS transpose chunks (tbuf @ smem base)
  ushort_t* tbuf = (ushort_t*)smem;   // 64*132 halfs = 16896B
  for (int c = 0; c < 8; ++c) {
    __syncthreads();
    if (w == c) {
#pragma unroll
      for (int nt = 0; nt < 4; ++nt) {
        int r = nt * 16 + n16;
#pragma unroll
        for (int S = 0; S < 4; ++S) {
          int k = 32 * S + 8 * g;
          *(uint2*)&tbuf[r * 132 + k] = make_uint2(breg[nt][S].x, breg[nt][S].y);
          *(uint2*)&tbuf[r * 132 + k + 4] = make_uint2(breg[nt][S].z, breg[nt][S].w);
        }
      }
    }
    __syncthreads();
    const size_t obase = ((size_t)d * BB + bx * 512 + c * 64) * NN;
    for (int idx = tid; idx < 64 * NN; idx += TPB) {
      int rl = idx / NN;
      int col = idx - rl * NN;
      out[obase + idx] = __half2float(__ushort_as_half(tbuf[rl * 132 + col]));
    }
  }
}

// ======================= launch =======================
extern "C" void kernel_launch(void* const* d_in, const int* in_sizes, int n_in,
                              void* d_out, int out_size, void* d_ws, size_t ws_size,
                              hipStream_t stream) {
  const float* x     = (const float*)d_in[0];
  const float* A     = (const float*)d_in[1];
  const int* order   = (const int*)d_in[2];
  const int* do_idx  = (const int*)d_in[3];
  const float* W1    = (const float*)d_in[4];
  const float* b1    = (const float*)d_in[5];
  const float* W2    = (const float*)d_in[6];
  const float* b2    = (const float*)d_in[7];
  float* out = (float*)d_out;

  char* ws = (char*)d_ws;
  const size_t XTH_B = (size_t)BB * NN * 2;         // 1,638,400
  const size_t W1M_B = (size_t)DD * NN * 4096 * 2;  // 26,214,400
  ushort_t* xTh = (ushort_t*)ws;
  ushort_t* W1M = (ushort_t*)(ws + XTH_B);
  uint_t* epi   = (uint_t*)(ws + XTH_B + W1M_B);    // 8,000 B

  hipLaunchKernelGGL(prep_xth, dim3((BB * NN) / 256), dim3(256), 0, stream, x, xTh);
  hipLaunchKernelGGL(prep_w1m, dim3((DD * NN * 4096) / 256), dim3(256), 0, stream,
                     A, W1, b1, W1M);
  hipLaunchKernelGGL(prep_epi3, dim3((NN * 20 + 255) / 256), dim3(256), 0, stream,
                     W2, b2, epi);
  hipLaunchKernelGGL(dag_mfma_ss, dim3(BB / 512, DD), dim3(TPB), 0, stream,
                     xTh, order, do_idx, W1M, epi, out);
}

// Round 9
// 268.642 us; speedup vs baseline: 3.4973x; 1.0235x over previous
//
#include <hip/hip_runtime.h>
#include <hip/hip_fp16.h>

#define NN 100   // nodes
#define HH 32    // hidden
#define BB 8192  // batch
#define DD 32    // dags
#define KP 128   // padded K
#define TPB 512  // 8 waves per block

typedef _Float16 f16x8 __attribute__((ext_vector_type(8)));
typedef _Float16 f16x2 __attribute__((ext_vector_type(2)));
typedef __fp16 fph2 __attribute__((ext_vector_type(2)));
typedef float f32x4 __attribute__((ext_vector_type(4)));
typedef unsigned short ushort_t;
typedef unsigned int uint_t;
union FU { uint4 u; f16x8 h; };
union PU { fph2 p; f16x2 h; uint_t u; };

#define AS_GLOBAL __attribute__((address_space(1)))
#define AS_LDS    __attribute__((address_space(3)))

// ======================= prep =======================
// x (B,N) f32 -> xTh (N,B) fp16
__global__ void prep_xth(const float* __restrict__ x, ushort_t* __restrict__ xTh) {
  int idx = blockIdx.x * 256 + threadIdx.x;
  if (idx >= BB * NN) return;
  int b = idx & (BB - 1);
  int n = idx >> 13;
  xTh[idx] = __half_as_ushort(__float2half_rn(x[(size_t)b * NN + n]));
}

// W1M[d][node]: 32x128 fp16 tile, swizzled (j*128+k)^((j&7)<<3)
// k<100: mask*W1; k==100: x-weight; k==101: b1; else 0
__global__ void prep_w1m(const float* __restrict__ A, const float* __restrict__ W1,
                         const float* __restrict__ b1, ushort_t* __restrict__ W1M) {
  int idx = blockIdx.x * 256 + threadIdx.x;   // DD*NN*4096
  int tile = idx >> 12;
  int d = tile / NN;
  int node = tile - d * NN;
  int rem = idx & 4095;
  int j = rem >> 7;
  int k = rem & 127;
  float v = 0.f;
  if (k < NN) {
    float m = A[((size_t)d * NN + k) * NN + node];
    v = (m != 0.f) ? W1[((size_t)node * HH + j) * (NN + 1) + k] : 0.f;
  } else if (k == NN) {
    v = W1[((size_t)node * HH + j) * (NN + 1) + NN];
  } else if (k == NN + 1) {
    v = b1[node * HH + j];
  }
  int t = (j * KP + k) ^ ((j & 7) << 3);
  W1M[(size_t)tile * 4096 + t] = __half_as_ushort(__float2half_rn(v));
}

// epi3[node][20] uints: 0..15 = half2(W2[2c],W2[2c+1]); 16 = b2 bits; 17..19 pad
__global__ void prep_epi3(const float* __restrict__ W2, const float* __restrict__ b2,
                          uint_t* __restrict__ epi) {
  int idx = blockIdx.x * 256 + threadIdx.x;
  if (idx >= NN * 20) return;
  int node = idx / 20;
  int c = idx - node * 20;
  uint_t v = 0u;
  if (c < 16) {
    uint_t lo = __half_as_ushort(__float2half_rn(W2[node * HH + 2 * c]));
    uint_t hi = __half_as_ushort(__float2half_rn(W2[node * HH + 2 * c + 1]));
    v = lo | (hi << 16);
  } else if (c == 16) {
    v = __float_as_uint(b2[node]);
  }
  epi[idx] = v;
}

// ======================= main =======================
// LDS: tiles 2 sets x 4 x 8192B = 65536 @0; xstage 2 sets x 4096B @65536;
// epi 8000B @73728; total 81728 (<= 81920 -> 2 blocks/CU)
#define XS_OFF 65536
#define EPI_OFF 73728
#define SMEM_BYTES (73728 + 8000)

__global__ __launch_bounds__(TPB, 4) void dag_mfma_ss(
    const ushort_t* __restrict__ xTh,  // [N][B] fp16
    const int* __restrict__ order,     // [D][N]
    const int* __restrict__ do_idx_p,  // [1]
    const ushort_t* __restrict__ W1M,  // [D][N][4096] fp16 swizzled
    const uint_t* __restrict__ epi_g,  // [N][20]
    float* __restrict__ out)           // [D][B][N]
{
  __shared__ __align__(16) char smem[SMEM_BYTES];
  ushort_t* stage = (ushort_t*)smem;
  const char* sp = (const char*)smem;
  uint_t* epi_l = (uint_t*)(smem + EPI_OFF);

  const int d = blockIdx.y;
  const int bx = blockIdx.x;
  const int tid = threadIdx.x;
  const int w = tid >> 6;
  const int lane = tid & 63;
  const int g = lane >> 4;
  const int n16 = lane & 15;
  const int di = __builtin_amdgcn_readfirstlane(do_idx_p[0]);

  // epi preload (500 uint4)
  {
    const uint4* s4 = (const uint4*)epi_g;
    uint4* d4 = (uint4*)epi_l;
    for (int i = tid; i < 500; i += TPB) d4[i] = s4[i];
  }

  const ushort_t* Wd = W1M + (size_t)d * NN * 4096;
  const int* ord = order + d * NN;

  // per-lane swizzled ds_read byte offsets (within a tile), per S
  int vs[4];
#pragma unroll
  for (int S = 0; S < 4; ++S) {
    int hw = n16 * 128 + ((8 * g) ^ ((n16 & 3) << 3)) + 32 * (S ^ ((n16 >> 2) & 1));
    vs[S] = 2 * hw + 32768;   // +32768: loop-top XOR flips to set0 first
  }
  // x-stage byte base for this thread's wave rows (set-toggled alongside vs)
  int xso = XS_OFF + (w * 64 + n16) * 2 + 4096;   // + q*1024 + nt*32 at use

  // nodes + stage for superstep 0
  int nd[4], nn[4];
#pragma unroll
  for (int q = 0; q < 4; ++q) nd[q] = __builtin_amdgcn_readfirstlane(ord[q]);
#pragma unroll
  for (int q = 0; q < 4; ++q) {
    const ushort_t* gsrc = Wd + (size_t)nd[q] * 4096 + tid * 8;
    __builtin_amdgcn_global_load_lds((const AS_GLOBAL void*)gsrc,
        (AS_LDS void*)(stage + q * 4096 + (w << 9)), 16, 0, 0);
  }
#pragma unroll
  for (int q = 0; q < 4; ++q) {
    if (w == q) {   // wave-uniform; 64 lanes x 16B = 1KB column
      const ushort_t* gx = xTh + (size_t)nd[q] * BB + bx * 512 + lane * 8;
      __builtin_amdgcn_global_load_lds((const AS_GLOBAL void*)gx,
          (AS_LDS void*)(smem + XS_OFF + q * 1024), 16, 0, 0);
    }
  }

  // B-operand: breg[nt][S]: lane(g,n16) holds k=32S+8g+{0..7}, row = block
  // rows [bx*512 + w*64 + nt*16 + n16]; k=101 (S=3 .z hi, g==0) = 1.0 (b1 row)
  uint4 breg[4][4];
#pragma unroll
  for (int nt = 0; nt < 4; ++nt) {
#pragma unroll
    for (int S = 0; S < 4; ++S) breg[nt][S] = make_uint4(0u, 0u, 0u, 0u);
    breg[nt][3].z = (g == 0) ? 0x3C000000u : 0u;
  }

  const f32x4 zero4 = {0.f, 0.f, 0.f, 0.f};
  PU c001; c001.u = 0x211F211Fu;   // fp16 0.01 x2

#pragma unroll 1
  for (int ss = 0; ss < 25; ++ss) {
    // superstep top: everything outstanding is exactly what we need
    asm volatile("s_waitcnt vmcnt(0) lgkmcnt(0)" ::: "memory");
    __builtin_amdgcn_s_barrier();
    __builtin_amdgcn_sched_barrier(0);

#pragma unroll
    for (int S = 0; S < 4; ++S) vs[S] ^= 32768;   // toggle tile set
    xso ^= 4096;                                   // toggle x set

    const bool more = (ss < 24);
    if (more) {
      // issue next superstep's tiles + x columns into the other set
#pragma unroll
      for (int q = 0; q < 4; ++q)
        nn[q] = __builtin_amdgcn_readfirstlane(ord[4 * (ss + 1) + q]);
      const int dsts = (((ss + 1) & 1) << 14);   // halfword offset of tile set
#pragma unroll
      for (int q = 0; q < 4; ++q) {
        const ushort_t* gsrc = Wd + (size_t)nn[q] * 4096 + tid * 8;
        __builtin_amdgcn_global_load_lds((const AS_GLOBAL void*)gsrc,
            (AS_LDS void*)(stage + dsts + q * 4096 + (w << 9)), 16, 0, 0);
      }
      const int xdst = XS_OFF + (((ss + 1) & 1) << 12);
#pragma unroll
      for (int q = 0; q < 4; ++q) {
        if (w == q) {
          const ushort_t* gx = xTh + (size_t)nn[q] * BB + bx * 512 + lane * 8;
          __builtin_amdgcn_global_load_lds((const AS_GLOBAL void*)gx,
              (AS_LDS void*)(smem + xdst + q * 1024), 16, 0, 0);
        }
      }
    }

    // ---- 4 steps, barrier-free
#pragma unroll
    for (int q = 0; q < 4; ++q) {
      const int node = nd[q];

      // x bits for this step's 4 row-tiles (fp16, from LDS)
      ushort_t xb[4];
#pragma unroll
      for (int nt = 0; nt < 4; ++nt)
        xb[nt] = *(const ushort_t*)(sp + xso + q * 1024 + nt * 32);

      // insert x at k=100 (S=3 .z lo, owner g==0); hi half is always 1.0
#pragma unroll
      for (int nt = 0; nt < 4; ++nt) {
        uint_t ins = 0x3C000000u | (uint_t)xb[nt];
        breg[nt][3].z = (g == 0) ? ins : breg[nt][3].z;
      }

      float val[4];
      if (node != di) {
        const char* ep = (const char*)epi_l + node * 80;
        const float b2n = *(const float*)(ep + 64);

        f32x4 acc[4];
        float p0[4];

        // ---- phase 0: j = 4g + r4 (tile row n16)
        {
          __builtin_amdgcn_s_setprio(1);
#pragma unroll
          for (int S = 0; S < 4; ++S) {
            FU a0;
            a0.u = *(const uint4*)(sp + vs[S] + q * 8192);
#pragma unroll
            for (int nt = 0; nt < 4; ++nt) {
              FU bu; bu.u = breg[nt][S];
              if (S == 0)
                acc[nt] = __builtin_amdgcn_mfma_f32_16x16x32_f16(a0.h, bu.h, zero4, 0, 0, 0);
              else
                acc[nt] = __builtin_amdgcn_mfma_f32_16x16x32_f16(a0.h, bu.h, acc[nt], 0, 0, 0);
            }
          }
          __builtin_amdgcn_s_setprio(0);
          const uint2 wlo = *(const uint2*)(ep + 8 * g);   // j=4g..4g+3 as half2 x2
          PU w01, w23; w01.u = wlo.x; w23.u = wlo.y;
#pragma unroll
          for (int nt = 0; nt < 4; ++nt) {
            PU h01, h23;
            h01.p = __builtin_amdgcn_cvt_pkrtz(acc[nt][0], acc[nt][1]);
            h23.p = __builtin_amdgcn_cvt_pkrtz(acc[nt][2], acc[nt][3]);
            h01.p = __builtin_elementwise_max(h01.p, h01.p * c001.p);
            h23.p = __builtin_elementwise_max(h23.p, h23.p * c001.p);
            float p = __builtin_amdgcn_fdot2(h01.h, w01.h, 0.f, false);
            p0[nt] = __builtin_amdgcn_fdot2(h23.h, w23.h, p, false);
          }
        }

        // ---- phase 1: j = 16 + 4g + r4 (tile row 16+n16), reuse acc regs
        {
          __builtin_amdgcn_s_setprio(1);
#pragma unroll
          for (int S = 0; S < 4; ++S) {
            FU a1;
            a1.u = *(const uint4*)(sp + vs[S] + q * 8192 + 4096);
#pragma unroll
            for (int nt = 0; nt < 4; ++nt) {
              FU bu; bu.u = breg[nt][S];
              if (S == 0)
                acc[nt] = __builtin_amdgcn_mfma_f32_16x16x32_f16(a1.h, bu.h, zero4, 0, 0, 0);
              else
                acc[nt] = __builtin_amdgcn_mfma_f32_16x16x32_f16(a1.h, bu.h, acc[nt], 0, 0, 0);
            }
          }
          __builtin_amdgcn_s_setprio(0);
          const uint2 whi = *(const uint2*)(ep + 32 + 8 * g);  // j=16+4g..
          PU w45, w67; w45.u = whi.x; w67.u = whi.y;
#pragma unroll
          for (int nt = 0; nt < 4; ++nt) {
            PU h45, h67;
            h45.p = __builtin_amdgcn_cvt_pkrtz(acc[nt][0], acc[nt][1]);
            h67.p = __builtin_amdgcn_cvt_pkrtz(acc[nt][2], acc[nt][3]);
            h45.p = __builtin_elementwise_max(h45.p, h45.p * c001.p);
            h67.p = __builtin_elementwise_max(h67.p, h67.p * c001.p);
            float p = __builtin_amdgcn_fdot2(h45.h, w45.h, p0[nt], false);
            p = __builtin_amdgcn_fdot2(h67.h, w67.h, p, false);
            p += __shfl_xor(p, 16, 64);
            p += __shfl_xor(p, 32, 64);
            val[nt] = p + b2n;
          }
        }
      } else {
#pragma unroll
        for (int nt = 0; nt < 4; ++nt)
          val[nt] = __half2float(__ushort_as_half(xb[nt]));
      }

      // insert val (fp16) at k=node: wave-uniform selects
      const int sn = node >> 5;
      const int en2 = (node >> 1) & 3;
      const int gn = (node >> 3) & 3;
      const int hin = node & 1;
      const bool own = (g == gn);
      ushort_t hv[4];
#pragma unroll
      for (int nt = 0; nt < 4; ++nt) hv[nt] = __half_as_ushort(__float2half_rn(val[nt]));
#pragma unroll
      for (int S = 0; S < 4; ++S) {
        if (S != sn) continue;    // uniform
#pragma unroll
        for (int nt = 0; nt < 4; ++nt) {
          uint4& Bq = breg[nt][S];
          uint_t hvn = (uint_t)hv[nt];
          if (en2 == 0) {
            uint_t old = Bq.x;
            uint_t nw = hin ? ((old & 0x0000FFFFu) | (hvn << 16)) : ((old & 0xFFFF0000u) | hvn);
            Bq.x = own ? nw : old;
          } else if (en2 == 1) {
            uint_t old = Bq.y;
            uint_t nw = hin ? ((old & 0x0000FFFFu) | (hvn << 16)) : ((old & 0xFFFF0000u) | hvn);
            Bq.y = own ? nw : old;
          } else if (en2 == 2) {
            uint_t old = Bq.z;
            uint_t nw = hin ? ((old & 0x0000FFFFu) | (hvn << 16)) : ((old & 0xFFFF0000u) | hvn);
            Bq.z = own ? nw : old;
          } else {
            uint_t old = Bq.w;
            uint_t nw = hin ? ((old & 0x0000FFFFu) | (hvn << 16)) : ((old & 0xFFFF0000u) | hvn);
            Bq.w = own ? nw : old;
          }
        }
      }
    }

#pragma unroll
    for (int q = 0; q < 4; ++q) nd[q] = nn[q];
  }

  // ---- output: per-wave 64-row LDS transpose chunks (tbuf @ smem base)
  ushort_t* tbuf = (ushort_t*)smem;   // 64*132 halfs = 16896B
  for (int c = 0; c < 8; ++c) {
    __syncthreads();
    if (w == c) {
#pragma unroll
      for (int nt = 0; nt < 4; ++nt) {
        int r = nt * 16 + n16;
#pragma unroll
        for (int S = 0; S < 4; ++S) {
          int k = 32 * S + 8 * g;
          *(uint2*)&tbuf[r * 132 + k] = make_uint2(breg[nt][S].x, breg[nt][S].y);
          *(uint2*)&tbuf[r * 132 + k + 4] = make_uint2(breg[nt][S].z, breg[nt][S].w);
        }
      }
    }
    __syncthreads();
    const size_t obase = ((size_t)d * BB + bx * 512 + c * 64) * NN;
    for (int idx = tid; idx < 64 * NN; idx += TPB) {
      int rl = idx / NN;
      int col = idx - rl * NN;
      out[obase + idx] = __half2float(__ushort_as_half(tbuf[rl * 132 + col]));
    }
  }
}

// ======================= launch =======================
extern "C" void kernel_launch(void* const* d_in, const int* in_sizes, int n_in,
                              void* d_out, int out_size, void* d_ws, size_t ws_size,
                              hipStream_t stream) {
  const float* x     = (const float*)d_in[0];
  const float* A     = (const float*)d_in[1];
  const int* order   = (const int*)d_in[2];
  const int* do_idx  = (const int*)d_in[3];
  const float* W1    = (const float*)d_in[4];
  const float* b1    = (const float*)d_in[5];
  const float* W2    = (const float*)d_in[6];
  const float* b2    = (const float*)d_in[7];
  float* out = (float*)d_out;

  char* ws = (char*)d_ws;
  const size_t XTH_B = (size_t)BB * NN * 2;         // 1,638,400
  const size_t W1M_B = (size_t)DD * NN * 4096 * 2;  // 26,214,400
  ushort_t* xTh = (ushort_t*)ws;
  ushort_t* W1M = (ushort_t*)(ws + XTH_B);
  uint_t* epi   = (uint_t*)(ws + XTH_B + W1M_B);    // 8,000 B

  hipLaunchKernelGGL(prep_xth, dim3((BB * NN) / 256), dim3(256), 0, stream, x, xTh);
  hipLaunchKernelGGL(prep_w1m, dim3((DD * NN * 4096) / 256), dim3(256), 0, stream,
                     A, W1, b1, W1M);
  hipLaunchKernelGGL(prep_epi3, dim3((NN * 20 + 255) / 256), dim3(256), 0, stream,
                     W2, b2, epi);
  hipLaunchKernelGGL(dag_mfma_ss, dim3(BB / 512, DD), dim3(TPB), 0, stream,
                     xTh, order, do_idx, W1M, epi, out);
}

// Round 10
// 265.818 us; speedup vs baseline: 3.5345x; 1.0106x over previous
//
#include <hip/hip_runtime.h>
#include <hip/hip_fp16.h>

#define NN 100   // nodes
#define HH 32    // hidden
#define BB 8192  // batch
#define DD 32    // dags
#define KP 128   // padded K
#define TPB 1024 // 16 waves per block, 32 rows per wave

typedef _Float16 f16x8 __attribute__((ext_vector_type(8)));
typedef _Float16 f16x2 __attribute__((ext_vector_type(2)));
typedef __fp16 fph2 __attribute__((ext_vector_type(2)));
typedef float f32x4 __attribute__((ext_vector_type(4)));
typedef unsigned short ushort_t;
typedef unsigned int uint_t;
union FU { uint4 u; f16x8 h; };
union PU { fph2 p; f16x2 h; uint_t u; };

#define AS_GLOBAL __attribute__((address_space(1)))
#define AS_LDS    __attribute__((address_space(3)))

// ======================= prep =======================
// x (B,N) f32 -> xTh (N,B) fp16
__global__ void prep_xth(const float* __restrict__ x, ushort_t* __restrict__ xTh) {
  int idx = blockIdx.x * 256 + threadIdx.x;
  if (idx >= BB * NN) return;
  int b = idx & (BB - 1);
  int n = idx >> 13;
  xTh[idx] = __half_as_ushort(__float2half_rn(x[(size_t)b * NN + n]));
}

// W1M[d][node]: 32x128 fp16 tile, swizzled (j*128+k)^((j&7)<<3)
// k<100: mask*W1; k==100: x-weight; k==101: b1; else 0
__global__ void prep_w1m(const float* __restrict__ A, const float* __restrict__ W1,
                         const float* __restrict__ b1, ushort_t* __restrict__ W1M) {
  int idx = blockIdx.x * 256 + threadIdx.x;   // DD*NN*4096
  int tile = idx >> 12;
  int d = tile / NN;
  int node = tile - d * NN;
  int rem = idx & 4095;
  int j = rem >> 7;
  int k = rem & 127;
  float v = 0.f;
  if (k < NN) {
    float m = A[((size_t)d * NN + k) * NN + node];
    v = (m != 0.f) ? W1[((size_t)node * HH + j) * (NN + 1) + k] : 0.f;
  } else if (k == NN) {
    v = W1[((size_t)node * HH + j) * (NN + 1) + NN];
  } else if (k == NN + 1) {
    v = b1[node * HH + j];
  }
  int t = (j * KP + k) ^ ((j & 7) << 3);
  W1M[(size_t)tile * 4096 + t] = __half_as_ushort(__float2half_rn(v));
}

// epi3[node][20] uints: 0..15 = half2(W2[2c],W2[2c+1]); 16 = b2 bits; 17..19 pad
__global__ void prep_epi3(const float* __restrict__ W2, const float* __restrict__ b2,
                          uint_t* __restrict__ epi) {
  int idx = blockIdx.x * 256 + threadIdx.x;
  if (idx >= NN * 20) return;
  int node = idx / 20;
  int c = idx - node * 20;
  uint_t v = 0u;
  if (c < 16) {
    uint_t lo = __half_as_ushort(__float2half_rn(W2[node * HH + 2 * c]));
    uint_t hi = __half_as_ushort(__float2half_rn(W2[node * HH + 2 * c + 1]));
    v = lo | (hi << 16);
  } else if (c == 16) {
    v = __float_as_uint(b2[node]);
  }
  epi[idx] = v;
}

// ======================= main =======================
// LDS: tiles 2 sets x 4 x 8192B = 65536 @0; xstage 2 sets x 4096B @65536;
// epi 8000B @73728; total 81728 (2 blocks/CU -> 32 waves/CU = HW max)
#define XS_OFF 65536
#define EPI_OFF 73728
#define SMEM_BYTES (73728 + 8000)

__global__ __launch_bounds__(TPB, 8) void dag_mfma_ss(
    const ushort_t* __restrict__ xTh,  // [N][B] fp16
    const int* __restrict__ order,     // [D][N]
    const int* __restrict__ do_idx_p,  // [1]
    const ushort_t* __restrict__ W1M,  // [D][N][4096] fp16 swizzled
    const uint_t* __restrict__ epi_g,  // [N][20]
    float* __restrict__ out)           // [D][B][N]
{
  __shared__ __align__(16) char smem[SMEM_BYTES];
  ushort_t* stage = (ushort_t*)smem;
  const char* sp = (const char*)smem;
  uint_t* epi_l = (uint_t*)(smem + EPI_OFF);

  const int d = blockIdx.y;
  const int bx = blockIdx.x;
  const int tid = threadIdx.x;
  const int w = tid >> 6;        // 16 waves
  const int lane = tid & 63;
  const int g = lane >> 4;
  const int n16 = lane & 15;
  const int di = __builtin_amdgcn_readfirstlane(do_idx_p[0]);

  // epi preload (500 uint4)
  {
    const uint4* s4 = (const uint4*)epi_g;
    uint4* d4 = (uint4*)epi_l;
    for (int i = tid; i < 500; i += TPB) d4[i] = s4[i];
  }

  const ushort_t* Wd = W1M + (size_t)d * NN * 4096;
  const int* ord = order + d * NN;

  // per-lane swizzled ds_read byte offsets (within a tile), per S
  int vs[4];
#pragma unroll
  for (int S = 0; S < 4; ++S) {
    int hw = n16 * 128 + ((8 * g) ^ ((n16 & 3) << 3)) + 32 * (S ^ ((n16 >> 2) & 1));
    vs[S] = 2 * hw + 32768;   // +32768: loop-top XOR flips to set0 first
  }
  // x-stage byte base for this thread's wave rows (set-toggled alongside vs)
  int xso = XS_OFF + (w * 32 + n16) * 2 + 4096;   // + q*1024 + nt*32 at use

  // nodes + stage for superstep 0 (tiles: waves 0-7; x: waves 0-3)
  int nd[4], nn[4];
#pragma unroll
  for (int q = 0; q < 4; ++q) nd[q] = __builtin_amdgcn_readfirstlane(ord[q]);
  if (w < 8) {
#pragma unroll
    for (int q = 0; q < 4; ++q) {
      const ushort_t* gsrc = Wd + (size_t)nd[q] * 4096 + tid * 8;
      __builtin_amdgcn_global_load_lds((const AS_GLOBAL void*)gsrc,
          (AS_LDS void*)(stage + q * 4096 + (w << 9)), 16, 0, 0);
    }
  }
#pragma unroll
  for (int q = 0; q < 4; ++q) {
    if (w == q) {   // wave-uniform; 64 lanes x 16B = 1KB column
      const ushort_t* gx = xTh + (size_t)nd[q] * BB + bx * 512 + lane * 8;
      __builtin_amdgcn_global_load_lds((const AS_GLOBAL void*)gx,
          (AS_LDS void*)(smem + XS_OFF + q * 1024), 16, 0, 0);
    }
  }

  // B-operand: breg[nt][S]: lane(g,n16) holds k=32S+8g+{0..7}, row = block
  // rows [bx*512 + w*32 + nt*16 + n16]; k=101 (S=3 .z hi, g==0) = 1.0 (b1 row)
  uint4 breg[2][4];
#pragma unroll
  for (int nt = 0; nt < 2; ++nt) {
#pragma unroll
    for (int S = 0; S < 4; ++S) breg[nt][S] = make_uint4(0u, 0u, 0u, 0u);
    breg[nt][3].z = (g == 0) ? 0x3C000000u : 0u;
  }

  const f32x4 zero4 = {0.f, 0.f, 0.f, 0.f};
  PU c001; c001.u = 0x211F211Fu;   // fp16 0.01 x2

#pragma unroll 1
  for (int ss = 0; ss < 25; ++ss) {
    // superstep top: everything outstanding is exactly what we need
    asm volatile("s_waitcnt vmcnt(0) lgkmcnt(0)" ::: "memory");
    __builtin_amdgcn_s_barrier();
    __builtin_amdgcn_sched_barrier(0);

#pragma unroll
    for (int S = 0; S < 4; ++S) vs[S] ^= 32768;   // toggle tile set
    xso ^= 4096;                                   // toggle x set

    const bool more = (ss < 24);
    if (more) {
      // issue next superstep's tiles + x columns into the other set
#pragma unroll
      for (int q = 0; q < 4; ++q)
        nn[q] = __builtin_amdgcn_readfirstlane(ord[4 * (ss + 1) + q]);
      const int dsts = (((ss + 1) & 1) << 14);   // halfword offset of tile set
      if (w < 8) {
#pragma unroll
        for (int q = 0; q < 4; ++q) {
          const ushort_t* gsrc = Wd + (size_t)nn[q] * 4096 + tid * 8;
          __builtin_amdgcn_global_load_lds((const AS_GLOBAL void*)gsrc,
              (AS_LDS void*)(stage + dsts + q * 4096 + (w << 9)), 16, 0, 0);
        }
      }
      const int xdst = XS_OFF + (((ss + 1) & 1) << 12);
#pragma unroll
      for (int q = 0; q < 4; ++q) {
        if (w == q) {
          const ushort_t* gx = xTh + (size_t)nn[q] * BB + bx * 512 + lane * 8;
          __builtin_amdgcn_global_load_lds((const AS_GLOBAL void*)gx,
              (AS_LDS void*)(smem + xdst + q * 1024), 16, 0, 0);
        }
      }
    }

    // ---- 4 steps, barrier-free
#pragma unroll
    for (int q = 0; q < 4; ++q) {
      const int node = nd[q];

      // x bits for this step's 2 row-tiles (fp16, from LDS)
      ushort_t xb[2];
#pragma unroll
      for (int nt = 0; nt < 2; ++nt)
        xb[nt] = *(const ushort_t*)(sp + xso + q * 1024 + nt * 32);

      // insert x at k=100 (S=3 .z lo, owner g==0); hi half is always 1.0
#pragma unroll
      for (int nt = 0; nt < 2; ++nt) {
        uint_t ins = 0x3C000000u | (uint_t)xb[nt];
        breg[nt][3].z = (g == 0) ? ins : breg[nt][3].z;
      }

      float val[2];
      if (node != di) {
        const char* ep = (const char*)epi_l + node * 80;
        const float b2n = *(const float*)(ep + 64);

        f32x4 acc[2];
        float p0[2];

        // ---- phase 0: j = 4g + r4 (tile row n16)
        {
          __builtin_amdgcn_s_setprio(1);
#pragma unroll
          for (int S = 0; S < 4; ++S) {
            FU a0;
            a0.u = *(const uint4*)(sp + vs[S] + q * 8192);
#pragma unroll
            for (int nt = 0; nt < 2; ++nt) {
              FU bu; bu.u = breg[nt][S];
              if (S == 0)
                acc[nt] = __builtin_amdgcn_mfma_f32_16x16x32_f16(a0.h, bu.h, zero4, 0, 0, 0);
              else
                acc[nt] = __builtin_amdgcn_mfma_f32_16x16x32_f16(a0.h, bu.h, acc[nt], 0, 0, 0);
            }
          }
          __builtin_amdgcn_s_setprio(0);
          const uint2 wlo = *(const uint2*)(ep + 8 * g);   // j=4g..4g+3 as half2 x2
          PU w01, w23; w01.u = wlo.x; w23.u = wlo.y;
#pragma unroll
          for (int nt = 0; nt < 2; ++nt) {
            PU h01, h23;
            h01.p = __builtin_amdgcn_cvt_pkrtz(acc[nt][0], acc[nt][1]);
            h23.p = __builtin_amdgcn_cvt_pkrtz(acc[nt][2], acc[nt][3]);
            h01.p = __builtin_elementwise_max(h01.p, h01.p * c001.p);
            h23.p = __builtin_elementwise_max(h23.p, h23.p * c001.p);
            float p = __builtin_amdgcn_fdot2(h01.h, w01.h, 0.f, false);
            p0[nt] = __builtin_amdgcn_fdot2(h23.h, w23.h, p, false);
          }
        }

        // ---- phase 1: j = 16 + 4g + r4 (tile row 16+n16), reuse acc regs
        {
          __builtin_amdgcn_s_setprio(1);
#pragma unroll
          for (int S = 0; S < 4; ++S) {
            FU a1;
            a1.u = *(const uint4*)(sp + vs[S] + q * 8192 + 4096);
#pragma unroll
            for (int nt = 0; nt < 2; ++nt) {
              FU bu; bu.u = breg[nt][S];
              if (S == 0)
                acc[nt] = __builtin_amdgcn_mfma_f32_16x16x32_f16(a1.h, bu.h, zero4, 0, 0, 0);
              else
                acc[nt] = __builtin_amdgcn_mfma_f32_16x16x32_f16(a1.h, bu.h, acc[nt], 0, 0, 0);
            }
          }
          __builtin_amdgcn_s_setprio(0);
          const uint2 whi = *(const uint2*)(ep + 32 + 8 * g);  // j=16+4g..
          PU w45, w67; w45.u = whi.x; w67.u = whi.y;
#pragma unroll
          for (int nt = 0; nt < 2; ++nt) {
            PU h45, h67;
            h45.p = __builtin_amdgcn_cvt_pkrtz(acc[nt][0], acc[nt][1]);
            h67.p = __builtin_amdgcn_cvt_pkrtz(acc[nt][2], acc[nt][3]);
            h45.p = __builtin_elementwise_max(h45.p, h45.p * c001.p);
            h67.p = __builtin_elementwise_max(h67.p, h67.p * c001.p);
            float p = __builtin_amdgcn_fdot2(h45.h, w45.h, p0[nt], false);
            p = __builtin_amdgcn_fdot2(h67.h, w67.h, p, false);
            p += __shfl_xor(p, 16, 64);
            p += __shfl_xor(p, 32, 64);
            val[nt] = p + b2n;
          }
        }
      } else {
#pragma unroll
        for (int nt = 0; nt < 2; ++nt)
          val[nt] = __half2float(__ushort_as_half(xb[nt]));
      }

      // insert val (fp16) at k=node: wave-uniform selects
      const int sn = node >> 5;
      const int en2 = (node >> 1) & 3;
      const int gn = (node >> 3) & 3;
      const int hin = node & 1;
      const bool own = (g == gn);
      ushort_t hv[2];
#pragma unroll
      for (int nt = 0; nt < 2; ++nt) hv[nt] = __half_as_ushort(__float2half_rn(val[nt]));
#pragma unroll
      for (int S = 0; S < 4; ++S) {
        if (S != sn) continue;    // uniform
#pragma unroll
        for (int nt = 0; nt < 2; ++nt) {
          uint4& Bq = breg[nt][S];
          uint_t hvn = (uint_t)hv[nt];
          if (en2 == 0) {
            uint_t old = Bq.x;
            uint_t nw = hin ? ((old & 0x0000FFFFu) | (hvn << 16)) : ((old & 0xFFFF0000u) | hvn);
            Bq.x = own ? nw : old;
          } else if (en2 == 1) {
            uint_t old = Bq.y;
            uint_t nw = hin ? ((old & 0x0000FFFFu) | (hvn << 16)) : ((old & 0xFFFF0000u) | hvn);
            Bq.y = own ? nw : old;
          } else if (en2 == 2) {
            uint_t old = Bq.z;
            uint_t nw = hin ? ((old & 0x0000FFFFu) | (hvn << 16)) : ((old & 0xFFFF0000u) | hvn);
            Bq.z = own ? nw : old;
          } else {
            uint_t old = Bq.w;
            uint_t nw = hin ? ((old & 0x0000FFFFu) | (hvn << 16)) : ((old & 0xFFFF0000u) | hvn);
            Bq.w = own ? nw : old;
          }
        }
      }
    }

#pragma unroll
    for (int q = 0; q < 4; ++q) nd[q] = nn[q];
  }

  // ---- output: per-wave 32-row LDS transpose chunks (tbuf @ smem base)
  ushort_t* tbuf = (ushort_t*)smem;   // 32*132 halfs = 8448B
#pragma unroll 1
  for (int c = 0; c < 16; ++c) {
    __syncthreads();
    if (w == c) {
#pragma unroll
      for (int nt = 0; nt < 2; ++nt) {
        int r = nt * 16 + n16;
#pragma unroll
        for (int S = 0; S < 4; ++S) {
          int k = 32 * S + 8 * g;
          *(uint2*)&tbuf[r * 132 + k] = make_uint2(breg[nt][S].x, breg[nt][S].y);
          *(uint2*)&tbuf[r * 132 + k + 4] = make_uint2(breg[nt][S].z, breg[nt][S].w);
        }
      }
    }
    __syncthreads();
    const size_t obase = ((size_t)d * BB + bx * 512 + c * 32) * NN;
    for (int idx = tid; idx < 32 * NN; idx += TPB) {
      int rl = idx / NN;
      int col = idx - rl * NN;
      out[obase + idx] = __half2float(__ushort_as_half(tbuf[rl * 132 + col]));
    }
  }
}

// ======================= launch =======================
extern "C" void kernel_launch(void* const* d_in, const int* in_sizes, int n_in,
                              void* d_out, int out_size, void* d_ws, size_t ws_size,
                              hipStream_t stream) {
  const float* x     = (const float*)d_in[0];
  const float* A     = (const float*)d_in[1];
  const int* order   = (const int*)d_in[2];
  const int* do_idx  = (const int*)d_in[3];
  const float* W1    = (const float*)d_in[4];
  const float* b1    = (const float*)d_in[5];
  const float* W2    = (const float*)d_in[6];
  const float* b2    = (const float*)d_in[7];
  float* out = (float*)d_out;

  char* ws = (char*)d_ws;
  const size_t XTH_B = (size_t)BB * NN * 2;         // 1,638,400
  const size_t W1M_B = (size_t)DD * NN * 4096 * 2;  // 26,214,400
  ushort_t* xTh = (ushort_t*)ws;
  ushort_t* W1M = (ushort_t*)(ws + XTH_B);
  uint_t* epi   = (uint_t*)(ws + XTH_B + W1M_B);    // 8,000 B

  hipLaunchKernelGGL(prep_xth, dim3((BB * NN) / 256), dim3(256), 0, stream, x, xTh);
  hipLaunchKernelGGL(prep_w1m, dim3((DD * NN * 4096) / 256), dim3(256), 0, stream,
                     A, W1, b1, W1M);
  hipLaunchKernelGGL(prep_epi3, dim3((NN * 20 + 255) / 256), dim3(256), 0, stream,
                     W2, b2, epi);
  hipLaunchKernelGGL(dag_mfma_ss, dim3(BB / 512, DD), dim3(TPB), 0, stream,
                     xTh, order, do_idx, W1M, epi, out);
}